// Round 1
// baseline (593.498 us; speedup 1.0000x reference)
//
#include <hip/hip_runtime.h>

#define NEG_SLOPE 0.2f
#define LN_EPS 1e-5f

typedef float f2 __attribute__((ext_vector_type(2)));
typedef short s16x8 __attribute__((ext_vector_type(8)));
typedef float f32x4 __attribute__((ext_vector_type(4)));

__device__ __forceinline__ f2 sp2(float x){ return (f2){x, x}; }
__device__ __forceinline__ f2 fma2(f2 a, f2 b, f2 c){
#if __has_builtin(__builtin_elementwise_fma)
  return __builtin_elementwise_fma(a, b, c);
#else
  f2 r; r.x = fmaf(a.x, b.x, c.x); r.y = fmaf(a.y, b.y, c.y); return r;
#endif
}
__device__ __forceinline__ f2 max2(f2 a, f2 b){
#if __has_builtin(__builtin_elementwise_max)
  return __builtin_elementwise_max(a, b);
#else
  f2 r; r.x = fmaxf(a.x, b.x); r.y = fmaxf(a.y, b.y); return r;
#endif
}
__device__ __forceinline__ f2 min2(f2 a, f2 b){
#if __has_builtin(__builtin_elementwise_min)
  return __builtin_elementwise_min(a, b);
#else
  f2 r; r.x = fminf(a.x, b.x); r.y = fminf(a.y, b.y); return r;
#endif
}
__device__ __forceinline__ float wsum64(float v){
  #pragma unroll
  for (int o = 32; o >= 1; o >>= 1) v += __shfl_xor(v, o);
  return v;
}
// fp32 -> bf16 round-nearest-even
__device__ __forceinline__ unsigned short f2b(float f){
  unsigned u = __float_as_uint(f);
  return (unsigned short)((u + 0x7fffu + ((u >> 16) & 1u)) >> 16);
}

// ---------------- CSR build ----------------
__global__ void k_count(const int* __restrict__ dst, int* __restrict__ deg, int E){
  int e = blockIdx.x * blockDim.x + threadIdx.x;
  if (e < E) atomicAdd(&deg[dst[e]], 1);
}

__global__ void k_scan_blk(const int* __restrict__ deg, int* __restrict__ part,
                           int* __restrict__ sums, int n){
  __shared__ int buf[256];
  int t = threadIdx.x, i = blockIdx.x * 256 + t;
  int v = (i < n) ? deg[i] : 0;
  buf[t] = v; __syncthreads();
  #pragma unroll
  for (int off = 1; off < 256; off <<= 1){
    int x = (t >= off) ? buf[t - off] : 0;
    __syncthreads(); buf[t] += x; __syncthreads();
  }
  if (i < n) part[i] = buf[t] - v;
  if (t == 255) sums[blockIdx.x] = buf[255];
}

__global__ void k_scan_top(int* __restrict__ sums, int nb){
  __shared__ int buf[256];
  int t = threadIdx.x;
  int v = (t < nb) ? sums[t] : 0;
  buf[t] = v; __syncthreads();
  #pragma unroll
  for (int off = 1; off < 256; off <<= 1){
    int x = (t >= off) ? buf[t - off] : 0;
    __syncthreads(); buf[t] += x; __syncthreads();
  }
  if (t < nb) sums[t] = buf[t] - v;
}

__global__ void k_scan_add(int* __restrict__ ptr, const int* __restrict__ sums,
                           int n, int Etot){
  int i = blockIdx.x * 256 + threadIdx.x;
  if (i < n) ptr[i] += sums[blockIdx.x];
  if (i == 0) ptr[n] = Etot;
}

// CSR fill: scatter src AND the edge_attr row into CSR order (cea).
__global__ void k_fill(const int* __restrict__ dst, const int* __restrict__ src,
                       int* __restrict__ cnt, const int* __restrict__ ptr,
                       const float* __restrict__ ea, float* __restrict__ cea,
                       int* __restrict__ sx, int E){
  int e = blockIdx.x * blockDim.x + threadIdx.x;
  if (e < E){
    int d = dst[e];
    int pos = atomicAdd(&cnt[d], 1);
    int p = ptr[d] + pos;
    sx[p] = src[e];
    const float4* s4 = (const float4*)(ea + (size_t)e * 16);
    float4* d4 = (float4*)(cea + (size_t)p * 16);
    d4[0] = s4[0]; d4[1] = s4[1]; d4[2] = s4[2]; d4[3] = s4[3];
  }
}

// ---------------- bf16 convert + B-fragment pack ----------------
__global__ void k_cvt(const float* __restrict__ X, unsigned short* __restrict__ Xb,
                      long n4){
  long i = (long)blockIdx.x * blockDim.x + threadIdx.x;
  long i4 = i * 4;
  if (i4 < n4){
    float4 v = *(const float4*)(X + i4);
    ushort4 o; o.x = f2b(v.x); o.y = f2b(v.y); o.z = f2b(v.z); o.w = f2b(v.w);
    *(ushort4*)(Xb + i4) = o;
  }
}

// pack 5 [128,128] row-major fp32 matrices into MFMA B-fragment order:
// Bp[mat][c][q][lane][j] = bf16(W[q*32 + (lane>>4)*8 + j][c*16 + (lane&15)])
__global__ void k_pack(const float* __restrict__ w0, const float* __restrict__ w1,
                       const float* __restrict__ w2, const float* __restrict__ w3,
                       const float* __restrict__ w4, unsigned short* __restrict__ Bp){
  int id = blockIdx.x * blockDim.x + threadIdx.x;
  if (id >= 5 * 2048) return;
  int mat = id >> 11, rem = id & 2047;
  int c = rem >> 8, q = (rem >> 6) & 3, l = rem & 63;
  const float* W = mat == 0 ? w0 : mat == 1 ? w1 : mat == 2 ? w2 : mat == 3 ? w3 : w4;
  unsigned short* o = Bp + ((size_t)mat * 2048 + rem) * 8;
  int kb = q * 32 + (l >> 4) * 8;
  int col = c * 16 + (l & 15);
  #pragma unroll
  for (int j = 0; j < 8; j++) o[j] = f2b(W[(kb + j) * 128 + col]);
}

// ---------------- MFMA GEMM: Y[M,128] = A[M,128](bf16) @ W + b ----------------
__launch_bounds__(256)
__global__ void k_mm(const unsigned short* __restrict__ A,
                     const unsigned short* __restrict__ Bp,
                     const float* __restrict__ bias,
                     unsigned short* __restrict__ Yb, int M){
  const int ln = threadIdx.x & 63;
  const int rowBase = (blockIdx.x * 4 + (threadIdx.x >> 6)) * 16;
  const int r16 = ln & 15, quad = ln >> 4;
  int row = rowBase + r16; if (row >= M) row = M - 1;
  const unsigned short* ap = A + (size_t)row * 128 + quad * 8;
  s16x8 af[4];
  #pragma unroll
  for (int q = 0; q < 4; q++) af[q] = *(const s16x8*)(ap + q * 32);
  f32x4 acc[8];
  #pragma unroll
  for (int c = 0; c < 8; c++){
    acc[c] = (f32x4){0.f, 0.f, 0.f, 0.f};
    #pragma unroll
    for (int q = 0; q < 4; q++){
      s16x8 bf = *(const s16x8*)(Bp + ((size_t)(c * 4 + q) * 64 + ln) * 8);
      acc[c] = __builtin_amdgcn_mfma_f32_16x16x32_bf16(af[q], bf, acc[c], 0, 0, 0);
    }
  }
  #pragma unroll
  for (int c = 0; c < 8; c++){
    int col = c * 16 + r16;
    float bv = bias[col];
    #pragma unroll
    for (int r = 0; r < 4; r++){
      int orow = rowBase + quad * 4 + r;
      if (orow < M) Yb[(size_t)orow * 128 + col] = f2b(acc[c][r] + bv);
    }
  }
}

// fused pair: YL = A@WL + bL ; YR = A@WR + bR  (fp32 outputs)
__launch_bounds__(256)
__global__ void k_mm_lr(const unsigned short* __restrict__ A,
                        const unsigned short* __restrict__ BpL,
                        const unsigned short* __restrict__ BpR,
                        const float* __restrict__ bL, const float* __restrict__ bR,
                        float* __restrict__ YL, float* __restrict__ YR, int M){
  const int ln = threadIdx.x & 63;
  const int rowBase = (blockIdx.x * 4 + (threadIdx.x >> 6)) * 16;
  const int r16 = ln & 15, quad = ln >> 4;
  int row = rowBase + r16; if (row >= M) row = M - 1;
  const unsigned short* ap = A + (size_t)row * 128 + quad * 8;
  s16x8 af[4];
  #pragma unroll
  for (int q = 0; q < 4; q++) af[q] = *(const s16x8*)(ap + q * 32);
  f32x4 aL[8], aR[8];
  #pragma unroll
  for (int c = 0; c < 8; c++){
    aL[c] = (f32x4){0.f, 0.f, 0.f, 0.f};
    aR[c] = (f32x4){0.f, 0.f, 0.f, 0.f};
    #pragma unroll
    for (int q = 0; q < 4; q++){
      s16x8 bfl = *(const s16x8*)(BpL + ((size_t)(c * 4 + q) * 64 + ln) * 8);
      s16x8 bfr = *(const s16x8*)(BpR + ((size_t)(c * 4 + q) * 64 + ln) * 8);
      aL[c] = __builtin_amdgcn_mfma_f32_16x16x32_bf16(af[q], bfl, aL[c], 0, 0, 0);
      aR[c] = __builtin_amdgcn_mfma_f32_16x16x32_bf16(af[q], bfr, aR[c], 0, 0, 0);
    }
  }
  #pragma unroll
  for (int c = 0; c < 8; c++){
    int col = c * 16 + r16;
    float bvl = bL[col], bvr = bR[col];
    #pragma unroll
    for (int r = 0; r < 4; r++){
      int orow = rowBase + quad * 4 + r;
      if (orow < M){
        YL[(size_t)orow * 128 + col] = aL[c][r] + bvl;
        YR[(size_t)orow * 128 + col] = aR[c][r] + bvr;
      }
    }
  }
}

// ---------------- Fused GAT layer: wave/node, full-wave per item ----------------
// Lane t owns channels (2t, 2t+1); head = t>>4 (16 lanes per head).
// Chunk of <=64 CSR items: one coalesced sx load; sub-batches of 16:
//  phase A: 16 independent xl gathers issued back-to-back (v_readlane -> SGPR base)
//  phase B: consume in order (cea rows are sequential broadcast loads).
// Self loop via linearity: ee_self = (sum_e ee_e) / max(deg,1)  [exact algebra],
// so no precomputed loop_attr is needed at all.
#define EE16F2(A0, A1, A2, A3, EE) { \
  EE = sp2(A0.x) * we[0]; \
  EE = fma2(sp2(A0.y), we[1],  EE); EE = fma2(sp2(A0.z), we[2],  EE); \
  EE = fma2(sp2(A0.w), we[3],  EE); EE = fma2(sp2(A1.x), we[4],  EE); \
  EE = fma2(sp2(A1.y), we[5],  EE); EE = fma2(sp2(A1.z), we[6],  EE); \
  EE = fma2(sp2(A1.w), we[7],  EE); EE = fma2(sp2(A2.x), we[8],  EE); \
  EE = fma2(sp2(A2.y), we[9],  EE); EE = fma2(sp2(A2.z), we[10], EE); \
  EE = fma2(sp2(A2.w), we[11], EE); EE = fma2(sp2(A3.x), we[12], EE); \
  EE = fma2(sp2(A3.y), we[13], EE); EE = fma2(sp2(A3.z), we[14], EE); \
  EE = fma2(sp2(A3.w), we[15], EE); }

__launch_bounds__(256)
__global__ void k_gat(const float* __restrict__ xl, const float* __restrict__ xr,
                      const float* __restrict__ cea, const int* __restrict__ sx,
                      const int* __restrict__ ptr,
                      const float* __restrict__ We, const float* __restrict__ att,
                      const float* __restrict__ cbv,
                      float* __restrict__ hf, unsigned short* __restrict__ hb,
                      int N, int E, int wf, int wb){
  const int t = threadIdx.x & 63;
  const int n = blockIdx.x * 4 + (threadIdx.x >> 6);
  if (n >= N) return;
  const int c0 = 2 * t;

  f2 we[16];
  #pragma unroll
  for (int k = 0; k < 16; k++) we[k] = *(const f2*)(We + k * 128 + c0);
  const f2 atv = *(const f2*)(att + c0);
  const f2 cbf = *(const f2*)(cbv + c0);

  const int beg = __builtin_amdgcn_readfirstlane(ptr[n]);
  const int end = __builtin_amdgcn_readfirstlane(ptr[n + 1]);
  const int deg = end - beg;

  const f2 xrv = *(const f2*)(xr + (size_t)n * 128 + c0);
  const f2 xln = *(const f2*)(xl + (size_t)n * 128 + c0);

  f2 acc = sp2(0.f), eesum = sp2(0.f);
  float den = 0.f;

  for (int cbase = beg; cbase < end; cbase += 64){
    const int cn = __builtin_amdgcn_readfirstlane(min(64, end - cbase));
    int sv = (t < cn) ? sx[cbase + t] : 0;
    const float* ceac = cea + (size_t)cbase * 16;

    for (int sub = 0; sub < cn; sub += 16){
      // phase A: issue up to 16 independent gathers (depth-16 in flight)
      f2 xs[16];
      #pragma unroll
      for (int i = 0; i < 16; i++){
        int s = __builtin_amdgcn_readlane(sv, sub + i);   // 0 for invalid slots
        xs[i] = *(const f2*)(xl + (size_t)s * 128 + c0);
      }
      // phase B: consume in order
      #pragma unroll
      for (int i = 0; i < 16; i++){
        if (sub + i < cn){
          const float4* ep = (const float4*)(ceac + (size_t)(sub + i) * 16);
          float4 a0 = ep[0], a1 = ep[1], a2 = ep[2], a3 = ep[3];
          f2 ee;
          EE16F2(a0, a1, a2, a3, ee);
          eesum += ee;
          f2 m = xs[i] + xrv + ee;
          m = fma2(sp2(NEG_SLOPE), min2(m, sp2(0.f)), max2(m, sp2(0.f)));
          f2 pr = m * atv;
          float pl = pr.x + pr.y;
          pl += __shfl_xor(pl, 1); pl += __shfl_xor(pl, 2);
          pl += __shfl_xor(pl, 4); pl += __shfl_xor(pl, 8);
          float p = __expf(pl);
          den += p;
          acc = fma2(sp2(p), xs[i], acc);
        }
      }
    }
  }

  // self loop: ee_self = eesum / max(deg,1)
  {
    float rdeg = 1.f / fmaxf((float)deg, 1.f);
    f2 m = xln + xrv + eesum * sp2(rdeg);
    m = fma2(sp2(NEG_SLOPE), min2(m, sp2(0.f)), max2(m, sp2(0.f)));
    f2 pr = m * atv;
    float pl = pr.x + pr.y;
    pl += __shfl_xor(pl, 1); pl += __shfl_xor(pl, 2);
    pl += __shfl_xor(pl, 4); pl += __shfl_xor(pl, 8);
    float p = __expf(pl);
    den += p;
    acc = fma2(sp2(p), xln, acc);
  }

  float rd = 1.f / den;
  f2 o = fma2(acc, sp2(rd), cbf);
  float o0 = o.x > 0.f ? o.x : expm1f(o.x);
  float o1 = o.y > 0.f ? o.y : expm1f(o.y);
  if (wf) *(f2*)(hf + (size_t)n * 128 + c0) = (f2){o0, o1};
  if (wb){
    unsigned packed = (unsigned)f2b(o0) | ((unsigned)f2b(o1) << 16);
    *(unsigned*)(hb + (size_t)n * 128 + c0) = packed;
  }
}

// ---------------- LayerNorm + ReLU-MLP head ----------------
__launch_bounds__(256)
__global__ void k_head(const float* __restrict__ h, const float* __restrict__ g,
                       const float* __restrict__ b, const float* __restrict__ w1,
                       const float* __restrict__ b1, const float* __restrict__ w2,
                       const float* __restrict__ b2, float* __restrict__ out, int N){
  __shared__ float sn[4][128];
  const int t = threadIdx.x & 63, wv = threadIdx.x >> 6;
  const int node = blockIdx.x * 4 + wv;
  float h0 = 0.f, h1 = 0.f;
  if (node < N){ h0 = h[(size_t)node * 128 + t]; h1 = h[(size_t)node * 128 + 64 + t]; }
  float mu = wsum64(h0 + h1) * (1.f / 128.f);
  float d0 = h0 - mu, d1 = h1 - mu;
  float var = wsum64(d0 * d0 + d1 * d1) * (1.f / 128.f);
  float rstd = rsqrtf(var + LN_EPS);
  sn[wv][t]      = d0 * rstd * g[t]      + b[t];
  sn[wv][t + 64] = d1 * rstd * g[t + 64] + b[t + 64];
  __syncthreads();
  float a = b1[t];
  #pragma unroll
  for (int k4 = 0; k4 < 32; k4++){
    float4 v = *(const float4*)&sn[wv][k4 * 4];
    a = fmaf(v.x, w1[(k4 * 4 + 0) * 64 + t], a);
    a = fmaf(v.y, w1[(k4 * 4 + 1) * 64 + t], a);
    a = fmaf(v.z, w1[(k4 * 4 + 2) * 64 + t], a);
    a = fmaf(v.w, w1[(k4 * 4 + 3) * 64 + t], a);
  }
  a = fmaxf(a, 0.f);
  float p0 = a * w2[t * 3 + 0], p1 = a * w2[t * 3 + 1], p2 = a * w2[t * 3 + 2];
  p0 = wsum64(p0); p1 = wsum64(p1); p2 = wsum64(p2);
  if (node < N && t == 0){
    out[(size_t)node * 3 + 0] = p0 + b2[0];
    out[(size_t)node * 3 + 1] = p1 + b2[1];
    out[(size_t)node * 3 + 2] = p2 + b2[2];
  }
}

extern "C" void kernel_launch(void* const* d_in, const int* in_sizes, int n_in,
                              void* d_out, int out_size, void* d_ws, size_t ws_size,
                              hipStream_t stream){
  const float* x    = (const float*)d_in[0];
  const int*   ei   = (const int*)d_in[1];
  const float* ea   = (const float*)d_in[2];
  const float* in_w = (const float*)d_in[3];
  const float* in_b = (const float*)d_in[4];
  const float* Wl   = (const float*)d_in[5];
  const float* bl   = (const float*)d_in[6];
  const float* Wr   = (const float*)d_in[7];
  const float* br   = (const float*)d_in[8];
  const float* We   = (const float*)d_in[9];
  const float* att  = (const float*)d_in[10];
  const float* cb   = (const float*)d_in[11];
  const float* lng  = (const float*)d_in[12];
  const float* lnb  = (const float*)d_in[13];
  const float* h1w  = (const float*)d_in[14];
  const float* h1b  = (const float*)d_in[15];
  const float* h2w  = (const float*)d_in[16];
  const float* h2b  = (const float*)d_in[17];
  float* out = (float*)d_out;

  int N = in_sizes[0] / 128;
  int E = in_sizes[1] / 2;
  const int* src = ei;
  const int* dst = ei + E;

  char* w = (char*)d_ws;
  size_t off = 0;
  auto alloc = [&](size_t bytes) -> char* {
    char* p = w + off;
    off = (off + bytes + 255) & ~(size_t)255;
    return p;
  };
  int*   deg   = (int*)alloc((size_t)N * 4);
  int*   cnt   = (int*)alloc((size_t)N * 4);
  int*   ptr   = (int*)alloc((size_t)(N + 1) * 4);
  int*   bsum  = (int*)alloc(256 * 4);
  int*   sx    = (int*)alloc((size_t)E * 4);
  float* cea   = (float*)alloc((size_t)E * 16 * 4);
  unsigned short* xb    = (unsigned short*)alloc((size_t)N * 128 * 2);  // layer-0 gat bf16 out
  unsigned short* hb_in = (unsigned short*)alloc((size_t)N * 128 * 2);
  unsigned short* Bp    = (unsigned short*)alloc((size_t)5 * 16384 * 2);
  float* hf    = (float*)alloc((size_t)N * 128 * 4);
  float* xlb   = (float*)alloc((size_t)N * 128 * 4);
  float* xrb   = (float*)alloc((size_t)N * 128 * 4);

  int nb = (N + 255) / 256;
  hipMemsetAsync(deg, 0, (size_t)N * 4, stream);
  hipMemsetAsync(cnt, 0, (size_t)N * 4, stream);
  k_count<<<(E + 255) / 256, 256, 0, stream>>>(dst, deg, E);
  k_scan_blk<<<nb, 256, 0, stream>>>(deg, ptr, bsum, N);
  k_scan_top<<<1, 256, 0, stream>>>(bsum, nb);
  k_scan_add<<<nb, 256, 0, stream>>>(ptr, bsum, N, E);
  k_fill<<<(E + 255) / 256, 256, 0, stream>>>(dst, src, cnt, ptr, ea, cea, sx, E);

  long n4 = (long)N * 128;
  k_cvt<<<(int)((n4 / 4 + 255) / 256), 256, 0, stream>>>(x, xb, n4);
  k_pack<<<(5 * 2048 + 255) / 256, 256, 0, stream>>>(in_w, Wl, Wl + 16384, Wr, Wr + 16384, Bp);

  int gblocks = (N + 63) / 64;
  // in-proj: h = x @ in_w + in_b  (bf16 out)
  k_mm<<<gblocks, 256, 0, stream>>>(xb, Bp, in_b, hb_in, N);
  for (int l = 0; l < 2; l++){
    const unsigned short* Ain = (l == 0) ? hb_in : xb;  // layer-0 gat writes bf16 into xb
    k_mm_lr<<<gblocks, 256, 0, stream>>>(Ain, Bp + (size_t)(1 + l) * 16384,
                                         Bp + (size_t)(3 + l) * 16384,
                                         bl + l * 128, br + l * 128, xlb, xrb, N);
    k_gat<<<(N + 3) / 4, 256, 0, stream>>>(xlb, xrb, cea, sx, ptr,
                                           We + l * 2048, att + l * 128, cb + l * 128,
                                           hf, xb, N, E, (l == 1) ? 1 : 0, (l == 0) ? 1 : 0);
  }
  k_head<<<(N + 3) / 4, 256, 0, stream>>>(hf, lng, lnb, h1w, h1b, h2w, h2b, out, N);
}

// Round 2
// 548.009 us; speedup vs baseline: 1.0830x; 1.0830x over previous
//
#include <hip/hip_runtime.h>

#define NEG_SLOPE 0.2f
#define LN_EPS 1e-5f

typedef float f2 __attribute__((ext_vector_type(2)));
typedef short s16x8 __attribute__((ext_vector_type(8)));
typedef float f32x4 __attribute__((ext_vector_type(4)));

__device__ __forceinline__ f2 sp2(float x){ return (f2){x, x}; }
__device__ __forceinline__ f2 fma2(f2 a, f2 b, f2 c){
#if __has_builtin(__builtin_elementwise_fma)
  return __builtin_elementwise_fma(a, b, c);
#else
  f2 r; r.x = fmaf(a.x, b.x, c.x); r.y = fmaf(a.y, b.y, c.y); return r;
#endif
}
__device__ __forceinline__ f2 max2(f2 a, f2 b){
#if __has_builtin(__builtin_elementwise_max)
  return __builtin_elementwise_max(a, b);
#else
  f2 r; r.x = fmaxf(a.x, b.x); r.y = fmaxf(a.y, b.y); return r;
#endif
}
__device__ __forceinline__ f2 min2(f2 a, f2 b){
#if __has_builtin(__builtin_elementwise_min)
  return __builtin_elementwise_min(a, b);
#else
  f2 r; r.x = fminf(a.x, b.x); r.y = fminf(a.y, b.y); return r;
#endif
}
__device__ __forceinline__ float wsum64(float v){
  #pragma unroll
  for (int o = 32; o >= 1; o >>= 1) v += __shfl_xor(v, o);
  return v;
}
// fp32 -> bf16 round-nearest-even
__device__ __forceinline__ unsigned short f2b(float f){
  unsigned u = __float_as_uint(f);
  return (unsigned short)((u + 0x7fffu + ((u >> 16) & 1u)) >> 16);
}

// ---------------- CSR build ----------------
__global__ void k_count(const int* __restrict__ dst, int* __restrict__ deg, int E){
  int e = blockIdx.x * blockDim.x + threadIdx.x;
  if (e < E) atomicAdd(&deg[dst[e]], 1);
}

__global__ void k_scan_blk(const int* __restrict__ deg, int* __restrict__ part,
                           int* __restrict__ sums, int n){
  __shared__ int buf[256];
  int t = threadIdx.x, i = blockIdx.x * 256 + t;
  int v = (i < n) ? deg[i] : 0;
  buf[t] = v; __syncthreads();
  #pragma unroll
  for (int off = 1; off < 256; off <<= 1){
    int x = (t >= off) ? buf[t - off] : 0;
    __syncthreads(); buf[t] += x; __syncthreads();
  }
  if (i < n) part[i] = buf[t] - v;
  if (t == 255) sums[blockIdx.x] = buf[255];
}

__global__ void k_scan_top(int* __restrict__ sums, int nb){
  __shared__ int buf[256];
  int t = threadIdx.x;
  int v = (t < nb) ? sums[t] : 0;
  buf[t] = v; __syncthreads();
  #pragma unroll
  for (int off = 1; off < 256; off <<= 1){
    int x = (t >= off) ? buf[t - off] : 0;
    __syncthreads(); buf[t] += x; __syncthreads();
  }
  if (t < nb) sums[t] = buf[t] - v;
}

__global__ void k_scan_add(int* __restrict__ ptr, const int* __restrict__ sums,
                           int n, int Etot){
  int i = blockIdx.x * 256 + threadIdx.x;
  if (i < n) ptr[i] += sums[blockIdx.x];
  if (i == 0) ptr[n] = Etot;
}

// CSR fill: scatter src AND the edge_attr row into CSR order (cea).
__global__ void k_fill(const int* __restrict__ dst, const int* __restrict__ src,
                       int* __restrict__ cnt, const int* __restrict__ ptr,
                       const float* __restrict__ ea, float* __restrict__ cea,
                       int* __restrict__ sx, int E){
  int e = blockIdx.x * blockDim.x + threadIdx.x;
  if (e < E){
    int d = dst[e];
    int pos = atomicAdd(&cnt[d], 1);
    int p = ptr[d] + pos;
    sx[p] = src[e];
    const float4* s4 = (const float4*)(ea + (size_t)e * 16);
    float4* d4 = (float4*)(cea + (size_t)p * 16);
    d4[0] = s4[0]; d4[1] = s4[1]; d4[2] = s4[2]; d4[3] = s4[3];
  }
}

// ---------------- bf16 convert + B-fragment pack ----------------
__global__ void k_cvt(const float* __restrict__ X, unsigned short* __restrict__ Xb,
                      long n4){
  long i = (long)blockIdx.x * blockDim.x + threadIdx.x;
  long i4 = i * 4;
  if (i4 < n4){
    float4 v = *(const float4*)(X + i4);
    ushort4 o; o.x = f2b(v.x); o.y = f2b(v.y); o.z = f2b(v.z); o.w = f2b(v.w);
    *(ushort4*)(Xb + i4) = o;
  }
}

// pack 5 [128,128] row-major fp32 matrices into MFMA B-fragment order:
// Bp[mat][c][q][lane][j] = bf16(W[q*32 + (lane>>4)*8 + j][c*16 + (lane&15)])
__global__ void k_pack(const float* __restrict__ w0, const float* __restrict__ w1,
                       const float* __restrict__ w2, const float* __restrict__ w3,
                       const float* __restrict__ w4, unsigned short* __restrict__ Bp){
  int id = blockIdx.x * blockDim.x + threadIdx.x;
  if (id >= 5 * 2048) return;
  int mat = id >> 11, rem = id & 2047;
  int c = rem >> 8, q = (rem >> 6) & 3, l = rem & 63;
  const float* W = mat == 0 ? w0 : mat == 1 ? w1 : mat == 2 ? w2 : mat == 3 ? w3 : w4;
  unsigned short* o = Bp + ((size_t)mat * 2048 + rem) * 8;
  int kb = q * 32 + (l >> 4) * 8;
  int col = c * 16 + (l & 15);
  #pragma unroll
  for (int j = 0; j < 8; j++) o[j] = f2b(W[(kb + j) * 128 + col]);
}

// ---------------- MFMA GEMM: Y[M,128] = A[M,128](bf16) @ W + b ----------------
__launch_bounds__(256)
__global__ void k_mm(const unsigned short* __restrict__ A,
                     const unsigned short* __restrict__ Bp,
                     const float* __restrict__ bias,
                     unsigned short* __restrict__ Yb, int M){
  const int ln = threadIdx.x & 63;
  const int rowBase = (blockIdx.x * 4 + (threadIdx.x >> 6)) * 16;
  const int r16 = ln & 15, quad = ln >> 4;
  int row = rowBase + r16; if (row >= M) row = M - 1;
  const unsigned short* ap = A + (size_t)row * 128 + quad * 8;
  s16x8 af[4];
  #pragma unroll
  for (int q = 0; q < 4; q++) af[q] = *(const s16x8*)(ap + q * 32);
  f32x4 acc[8];
  #pragma unroll
  for (int c = 0; c < 8; c++){
    acc[c] = (f32x4){0.f, 0.f, 0.f, 0.f};
    #pragma unroll
    for (int q = 0; q < 4; q++){
      s16x8 bf = *(const s16x8*)(Bp + ((size_t)(c * 4 + q) * 64 + ln) * 8);
      acc[c] = __builtin_amdgcn_mfma_f32_16x16x32_bf16(af[q], bf, acc[c], 0, 0, 0);
    }
  }
  #pragma unroll
  for (int c = 0; c < 8; c++){
    int col = c * 16 + r16;
    float bv = bias[col];
    #pragma unroll
    for (int r = 0; r < 4; r++){
      int orow = rowBase + quad * 4 + r;
      if (orow < M) Yb[(size_t)orow * 128 + col] = f2b(acc[c][r] + bv);
    }
  }
}

// fused pair: YL = A@WL + bL ; YR = A@WR + bR  (fp32 outputs)
__launch_bounds__(256)
__global__ void k_mm_lr(const unsigned short* __restrict__ A,
                        const unsigned short* __restrict__ BpL,
                        const unsigned short* __restrict__ BpR,
                        const float* __restrict__ bL, const float* __restrict__ bR,
                        float* __restrict__ YL, float* __restrict__ YR, int M){
  const int ln = threadIdx.x & 63;
  const int rowBase = (blockIdx.x * 4 + (threadIdx.x >> 6)) * 16;
  const int r16 = ln & 15, quad = ln >> 4;
  int row = rowBase + r16; if (row >= M) row = M - 1;
  const unsigned short* ap = A + (size_t)row * 128 + quad * 8;
  s16x8 af[4];
  #pragma unroll
  for (int q = 0; q < 4; q++) af[q] = *(const s16x8*)(ap + q * 32);
  f32x4 aL[8], aR[8];
  #pragma unroll
  for (int c = 0; c < 8; c++){
    aL[c] = (f32x4){0.f, 0.f, 0.f, 0.f};
    aR[c] = (f32x4){0.f, 0.f, 0.f, 0.f};
    #pragma unroll
    for (int q = 0; q < 4; q++){
      s16x8 bfl = *(const s16x8*)(BpL + ((size_t)(c * 4 + q) * 64 + ln) * 8);
      s16x8 bfr = *(const s16x8*)(BpR + ((size_t)(c * 4 + q) * 64 + ln) * 8);
      aL[c] = __builtin_amdgcn_mfma_f32_16x16x32_bf16(af[q], bfl, aL[c], 0, 0, 0);
      aR[c] = __builtin_amdgcn_mfma_f32_16x16x32_bf16(af[q], bfr, aR[c], 0, 0, 0);
    }
  }
  #pragma unroll
  for (int c = 0; c < 8; c++){
    int col = c * 16 + r16;
    float bvl = bL[col], bvr = bR[col];
    #pragma unroll
    for (int r = 0; r < 4; r++){
      int orow = rowBase + quad * 4 + r;
      if (orow < M){
        YL[(size_t)orow * 128 + col] = aL[c][r] + bvl;
        YR[(size_t)orow * 128 + col] = aR[c][r] + bvr;
      }
    }
  }
}

// ---------------- Fused GAT layer ----------------
// Wave/node; lane t owns channels (2t,2t+1); head = t>>4.
// v2: - cea chunk staged to LDS once per chunk (coalesced), layout [j][item]
//       so staging writes are lane-consecutive and phase-B reads broadcast.
//     - branchless phase B (multiplicative validity mask, clamped LDS index),
//       ee chain split 8+8 so the scheduler can interleave items.
//     - grid-stride over nodes (2048 blocks) to avoid CP dispatch-rate limit.
// Self loop via linearity: ee_self = (sum_e ee_e) / max(deg,1).
__launch_bounds__(256)
__global__ void k_gat(const float* __restrict__ xl, const float* __restrict__ xr,
                      const float* __restrict__ cea, const int* __restrict__ sx,
                      const int* __restrict__ ptr,
                      const float* __restrict__ We, const float* __restrict__ att,
                      const float* __restrict__ cbv,
                      float* __restrict__ hf, unsigned short* __restrict__ hb,
                      int N, int E, int wf, int wb){
  __shared__ float4 sea4[4][4][64];   // [wave][float4-idx][item] = 16 KB
  const int t = threadIdx.x & 63;
  const int wv = threadIdx.x >> 6;
  const int c0 = 2 * t;

  f2 we[16];
  #pragma unroll
  for (int k = 0; k < 16; k++) we[k] = *(const f2*)(We + k * 128 + c0);
  const f2 atv = *(const f2*)(att + c0);
  const f2 cbf = *(const f2*)(cbv + c0);

  for (int n = blockIdx.x * 4 + wv; n < N; n += gridDim.x * 4){
    const int beg = __builtin_amdgcn_readfirstlane(ptr[n]);
    const int end = __builtin_amdgcn_readfirstlane(ptr[n + 1]);
    const int deg = end - beg;

    const f2 xrv = *(const f2*)(xr + (size_t)n * 128 + c0);
    const f2 xln = *(const f2*)(xl + (size_t)n * 128 + c0);

    f2 acc = sp2(0.f), eesum = sp2(0.f);
    float den = 0.f;

    for (int cbase = beg; cbase < end; cbase += 64){
      const int cn = __builtin_amdgcn_readfirstlane(min(64, end - cbase));
      int sv = (t < cn) ? sx[cbase + t] : 0;
      // coalesced chunk stage: lane t loads row (cbase+t)
      const bool st = (t < cn);
      const float4* sp4 = (const float4*)(cea + (size_t)(cbase + (st ? t : 0)) * 16);
      float4 r0 = sp4[0], r1 = sp4[1], r2 = sp4[2], r3 = sp4[3];

      f2 xs[16];
      auto issueA = [&](int sub){
        #pragma unroll
        for (int i = 0; i < 16; i++){
          int s = __builtin_amdgcn_readlane(sv, sub + i);  // lanes >= cn hold 0
          xs[i] = *(const f2*)(xl + (size_t)s * 128 + c0);
        }
      };
      auto phaseB = [&](int sub){
        #pragma unroll
        for (int i = 0; i < 16; i++){
          const int item = sub + i;
          const float vm = (item < cn) ? 1.f : 0.f;
          const int it = (item < cn) ? item : 0;   // clamp: avoid 0*garbage(NaN)
          float4 a0 = sea4[wv][0][it];
          float4 a1 = sea4[wv][1][it];
          float4 a2 = sea4[wv][2][it];
          float4 a3 = sea4[wv][3][it];
          f2 e0, e1;
          e0 = sp2(a0.x) * we[0];
          e0 = fma2(sp2(a0.y), we[1],  e0);
          e0 = fma2(sp2(a0.z), we[2],  e0);
          e0 = fma2(sp2(a0.w), we[3],  e0);
          e0 = fma2(sp2(a1.x), we[4],  e0);
          e0 = fma2(sp2(a1.y), we[5],  e0);
          e0 = fma2(sp2(a1.z), we[6],  e0);
          e0 = fma2(sp2(a1.w), we[7],  e0);
          e1 = sp2(a2.x) * we[8];
          e1 = fma2(sp2(a2.y), we[9],  e1);
          e1 = fma2(sp2(a2.z), we[10], e1);
          e1 = fma2(sp2(a2.w), we[11], e1);
          e1 = fma2(sp2(a3.x), we[12], e1);
          e1 = fma2(sp2(a3.y), we[13], e1);
          e1 = fma2(sp2(a3.z), we[14], e1);
          e1 = fma2(sp2(a3.w), we[15], e1);
          f2 ee = e0 + e1;
          eesum = fma2(sp2(vm), ee, eesum);
          f2 m = xs[i] + xrv + ee;
          m = fma2(sp2(NEG_SLOPE), min2(m, sp2(0.f)), max2(m, sp2(0.f)));
          f2 pr = m * atv;
          float pl = pr.x + pr.y;
          pl += __shfl_xor(pl, 1); pl += __shfl_xor(pl, 2);
          pl += __shfl_xor(pl, 4); pl += __shfl_xor(pl, 8);
          float p = __expf(pl) * vm;
          den += p;
          acc = fma2(sp2(p), xs[i], acc);
        }
      };

      issueA(0);                       // gathers overlap the cea-row wait
      if (st){
        sea4[wv][0][t] = r0; sea4[wv][1][t] = r1;
        sea4[wv][2][t] = r2; sea4[wv][3][t] = r3;
      }
      phaseB(0);
      for (int sub = 16; sub < cn; sub += 16){
        issueA(sub);
        phaseB(sub);
      }
    }

    // self loop: ee_self = eesum / max(deg,1)
    {
      float rdeg = 1.f / fmaxf((float)deg, 1.f);
      f2 m = xln + xrv + eesum * sp2(rdeg);
      m = fma2(sp2(NEG_SLOPE), min2(m, sp2(0.f)), max2(m, sp2(0.f)));
      f2 pr = m * atv;
      float pl = pr.x + pr.y;
      pl += __shfl_xor(pl, 1); pl += __shfl_xor(pl, 2);
      pl += __shfl_xor(pl, 4); pl += __shfl_xor(pl, 8);
      float p = __expf(pl);
      den += p;
      acc = fma2(sp2(p), xln, acc);
    }

    float rd = 1.f / den;
    f2 o = fma2(acc, sp2(rd), cbf);
    float o0 = o.x > 0.f ? o.x : expm1f(o.x);
    float o1 = o.y > 0.f ? o.y : expm1f(o.y);
    if (wf) *(f2*)(hf + (size_t)n * 128 + c0) = (f2){o0, o1};
    if (wb){
      unsigned packed = (unsigned)f2b(o0) | ((unsigned)f2b(o1) << 16);
      *(unsigned*)(hb + (size_t)n * 128 + c0) = packed;
    }
  }
}

// ---------------- LayerNorm + ReLU-MLP head ----------------
// sn[wv] is wave-private: no __syncthreads needed. Grid-stride over nodes.
__launch_bounds__(256)
__global__ void k_head(const float* __restrict__ h, const float* __restrict__ g,
                       const float* __restrict__ b, const float* __restrict__ w1,
                       const float* __restrict__ b1, const float* __restrict__ w2,
                       const float* __restrict__ b2, float* __restrict__ out, int N){
  __shared__ float sn[4][128];
  const int t = threadIdx.x & 63, wv = threadIdx.x >> 6;
  for (int node = blockIdx.x * 4 + wv; node < N; node += gridDim.x * 4){
    float h0 = h[(size_t)node * 128 + t];
    float h1 = h[(size_t)node * 128 + 64 + t];
    float mu = wsum64(h0 + h1) * (1.f / 128.f);
    float d0 = h0 - mu, d1 = h1 - mu;
    float var = wsum64(d0 * d0 + d1 * d1) * (1.f / 128.f);
    float rstd = rsqrtf(var + LN_EPS);
    sn[wv][t]      = d0 * rstd * g[t]      + b[t];
    sn[wv][t + 64] = d1 * rstd * g[t + 64] + b[t + 64];
    float a = b1[t];
    #pragma unroll
    for (int k4 = 0; k4 < 32; k4++){
      float4 v = *(const float4*)&sn[wv][k4 * 4];
      a = fmaf(v.x, w1[(k4 * 4 + 0) * 64 + t], a);
      a = fmaf(v.y, w1[(k4 * 4 + 1) * 64 + t], a);
      a = fmaf(v.z, w1[(k4 * 4 + 2) * 64 + t], a);
      a = fmaf(v.w, w1[(k4 * 4 + 3) * 64 + t], a);
    }
    a = fmaxf(a, 0.f);
    float p0 = a * w2[t * 3 + 0], p1 = a * w2[t * 3 + 1], p2 = a * w2[t * 3 + 2];
    p0 = wsum64(p0); p1 = wsum64(p1); p2 = wsum64(p2);
    if (t == 0){
      out[(size_t)node * 3 + 0] = p0 + b2[0];
      out[(size_t)node * 3 + 1] = p1 + b2[1];
      out[(size_t)node * 3 + 2] = p2 + b2[2];
    }
  }
}

extern "C" void kernel_launch(void* const* d_in, const int* in_sizes, int n_in,
                              void* d_out, int out_size, void* d_ws, size_t ws_size,
                              hipStream_t stream){
  const float* x    = (const float*)d_in[0];
  const int*   ei   = (const int*)d_in[1];
  const float* ea   = (const float*)d_in[2];
  const float* in_w = (const float*)d_in[3];
  const float* in_b = (const float*)d_in[4];
  const float* Wl   = (const float*)d_in[5];
  const float* bl   = (const float*)d_in[6];
  const float* Wr   = (const float*)d_in[7];
  const float* br   = (const float*)d_in[8];
  const float* We   = (const float*)d_in[9];
  const float* att  = (const float*)d_in[10];
  const float* cb   = (const float*)d_in[11];
  const float* lng  = (const float*)d_in[12];
  const float* lnb  = (const float*)d_in[13];
  const float* h1w  = (const float*)d_in[14];
  const float* h1b  = (const float*)d_in[15];
  const float* h2w  = (const float*)d_in[16];
  const float* h2b  = (const float*)d_in[17];
  float* out = (float*)d_out;

  int N = in_sizes[0] / 128;
  int E = in_sizes[1] / 2;
  const int* src = ei;
  const int* dst = ei + E;

  char* w = (char*)d_ws;
  size_t off = 0;
  auto alloc = [&](size_t bytes) -> char* {
    char* p = w + off;
    off = (off + bytes + 255) & ~(size_t)255;
    return p;
  };
  int*   deg   = (int*)alloc((size_t)N * 4);
  int*   cnt   = (int*)alloc((size_t)N * 4);
  int*   ptr   = (int*)alloc((size_t)(N + 1) * 4);
  int*   bsum  = (int*)alloc(256 * 4);
  int*   sx    = (int*)alloc((size_t)E * 4);
  float* cea   = (float*)alloc((size_t)E * 16 * 4);
  unsigned short* xb    = (unsigned short*)alloc((size_t)N * 128 * 2);  // layer-0 gat bf16 out
  unsigned short* hb_in = (unsigned short*)alloc((size_t)N * 128 * 2);
  unsigned short* Bp    = (unsigned short*)alloc((size_t)5 * 16384 * 2);
  float* hf    = (float*)alloc((size_t)N * 128 * 4);
  float* xlb   = (float*)alloc((size_t)N * 128 * 4);
  float* xrb   = (float*)alloc((size_t)N * 128 * 4);

  int nb = (N + 255) / 256;
  hipMemsetAsync(deg, 0, (size_t)N * 4, stream);
  hipMemsetAsync(cnt, 0, (size_t)N * 4, stream);
  k_count<<<(E + 255) / 256, 256, 0, stream>>>(dst, deg, E);
  k_scan_blk<<<nb, 256, 0, stream>>>(deg, ptr, bsum, N);
  k_scan_top<<<1, 256, 0, stream>>>(bsum, nb);
  k_scan_add<<<nb, 256, 0, stream>>>(ptr, bsum, N, E);
  k_fill<<<(E + 255) / 256, 256, 0, stream>>>(dst, src, cnt, ptr, ea, cea, sx, E);

  long n4 = (long)N * 128;
  k_cvt<<<(int)((n4 / 4 + 255) / 256), 256, 0, stream>>>(x, xb, n4);
  k_pack<<<(5 * 2048 + 255) / 256, 256, 0, stream>>>(in_w, Wl, Wl + 16384, Wr, Wr + 16384, Bp);

  int gblocks = (N + 63) / 64;
  int nodeBlocks = (N + 3) / 4;
  int gatBlocks = nodeBlocks < 2048 ? nodeBlocks : 2048;
  // in-proj: h = x @ in_w + in_b  (bf16 out)
  k_mm<<<gblocks, 256, 0, stream>>>(xb, Bp, in_b, hb_in, N);
  for (int l = 0; l < 2; l++){
    const unsigned short* Ain = (l == 0) ? hb_in : xb;  // layer-0 gat writes bf16 into xb
    k_mm_lr<<<gblocks, 256, 0, stream>>>(Ain, Bp + (size_t)(1 + l) * 16384,
                                         Bp + (size_t)(3 + l) * 16384,
                                         bl + l * 128, br + l * 128, xlb, xrb, N);
    k_gat<<<gatBlocks, 256, 0, stream>>>(xlb, xrb, cea, sx, ptr,
                                         We + l * 2048, att + l * 128, cb + l * 128,
                                         hf, xb, N, E, (l == 1) ? 1 : 0, (l == 0) ? 1 : 0);
  }
  k_head<<<gatBlocks, 256, 0, stream>>>(hf, lng, lnb, h1w, h1b, h2w, h2b, out, N);
}

// Round 4
// 507.621 us; speedup vs baseline: 1.1692x; 1.0796x over previous
//
#include <hip/hip_runtime.h>

#define NEG_SLOPE 0.2f
#define LN_EPS 1e-5f

typedef float f2 __attribute__((ext_vector_type(2)));
typedef short s16x4 __attribute__((ext_vector_type(4)));
typedef short s16x8 __attribute__((ext_vector_type(8)));
typedef float f32x4 __attribute__((ext_vector_type(4)));

__device__ __forceinline__ f2 sp2(float x){ return (f2){x, x}; }
__device__ __forceinline__ f2 fma2(f2 a, f2 b, f2 c){
#if __has_builtin(__builtin_elementwise_fma)
  return __builtin_elementwise_fma(a, b, c);
#else
  f2 r; r.x = fmaf(a.x, b.x, c.x); r.y = fmaf(a.y, b.y, c.y); return r;
#endif
}
__device__ __forceinline__ f2 max2(f2 a, f2 b){
#if __has_builtin(__builtin_elementwise_max)
  return __builtin_elementwise_max(a, b);
#else
  f2 r; r.x = fmaxf(a.x, b.x); r.y = fmaxf(a.y, b.y); return r;
#endif
}
__device__ __forceinline__ f2 min2(f2 a, f2 b){
#if __has_builtin(__builtin_elementwise_min)
  return __builtin_elementwise_min(a, b);
#else
  f2 r; r.x = fminf(a.x, b.x); r.y = fminf(a.y, b.y); return r;
#endif
}
__device__ __forceinline__ float wsum64(float v){
  #pragma unroll
  for (int o = 32; o >= 1; o >>= 1) v += __shfl_xor(v, o);
  return v;
}
// fp32 -> bf16 round-nearest-even
__device__ __forceinline__ unsigned short f2b(float f){
  unsigned u = __float_as_uint(f);
  return (unsigned short)((u + 0x7fffu + ((u >> 16) & 1u)) >> 16);
}

// ---------------- CSR build ----------------
__global__ void k_count(const int* __restrict__ dst, int* __restrict__ deg, int E){
  int e = blockIdx.x * blockDim.x + threadIdx.x;
  if (e < E) atomicAdd(&deg[dst[e]], 1);
}

__global__ void k_scan_blk(const int* __restrict__ deg, int* __restrict__ part,
                           int* __restrict__ sums, int n){
  __shared__ int buf[256];
  int t = threadIdx.x, i = blockIdx.x * 256 + t;
  int v = (i < n) ? deg[i] : 0;
  buf[t] = v; __syncthreads();
  #pragma unroll
  for (int off = 1; off < 256; off <<= 1){
    int x = (t >= off) ? buf[t - off] : 0;
    __syncthreads(); buf[t] += x; __syncthreads();
  }
  if (i < n) part[i] = buf[t] - v;
  if (t == 255) sums[blockIdx.x] = buf[255];
}

__global__ void k_scan_top(int* __restrict__ sums, int nb){
  __shared__ int buf[256];
  int t = threadIdx.x;
  int v = (t < nb) ? sums[t] : 0;
  buf[t] = v; __syncthreads();
  #pragma unroll
  for (int off = 1; off < 256; off <<= 1){
    int x = (t >= off) ? buf[t - off] : 0;
    __syncthreads(); buf[t] += x; __syncthreads();
  }
  if (t < nb) sums[t] = buf[t] - v;
}

__global__ void k_scan_add(int* __restrict__ ptr, const int* __restrict__ sums,
                           int n, int Etot){
  int i = blockIdx.x * 256 + threadIdx.x;
  if (i < n) ptr[i] += sums[blockIdx.x];
  if (i == 0) ptr[n] = Etot;
}

// CSR fill: scatter src + edge_attr row (converted to bf16) into CSR order.
// ceab is [E+64][16] bf16 row-major (32B/row) -> feeds MFMA A-fragments in k_gat.
__global__ void k_fill(const int* __restrict__ dst, const int* __restrict__ src,
                       int* __restrict__ cnt, const int* __restrict__ ptr,
                       const float* __restrict__ ea, unsigned short* __restrict__ ceab,
                       int* __restrict__ sx, int E){
  int e = blockIdx.x * blockDim.x + threadIdx.x;
  if (e < E){
    int d = dst[e];
    int pos = atomicAdd(&cnt[d], 1);
    int p = ptr[d] + pos;
    sx[p] = src[e];
    const float4* s4 = (const float4*)(ea + (size_t)e * 16);
    float4 a0 = s4[0], a1 = s4[1], a2 = s4[2], a3 = s4[3];
    ushort4 o0 = {f2b(a0.x), f2b(a0.y), f2b(a0.z), f2b(a0.w)};
    ushort4 o1 = {f2b(a1.x), f2b(a1.y), f2b(a1.z), f2b(a1.w)};
    ushort4 o2 = {f2b(a2.x), f2b(a2.y), f2b(a2.z), f2b(a2.w)};
    ushort4 o3 = {f2b(a3.x), f2b(a3.y), f2b(a3.z), f2b(a3.w)};
    ushort4* d4 = (ushort4*)(ceab + (size_t)p * 16);
    d4[0] = o0; d4[1] = o1; d4[2] = o2; d4[3] = o3;
  }
}

// ---------------- bf16 convert + B-fragment pack ----------------
__global__ void k_cvt(const float* __restrict__ X, unsigned short* __restrict__ Xb,
                      long n4){
  long i = (long)blockIdx.x * blockDim.x + threadIdx.x;
  long i4 = i * 4;
  if (i4 < n4){
    float4 v = *(const float4*)(X + i4);
    ushort4 o; o.x = f2b(v.x); o.y = f2b(v.y); o.z = f2b(v.z); o.w = f2b(v.w);
    *(ushort4*)(Xb + i4) = o;
  }
}

// pack 5 [128,128] row-major fp32 matrices into MFMA B-fragment order:
// Bp[mat][c][q][lane][j] = bf16(W[q*32 + (lane>>4)*8 + j][c*16 + (lane&15)])
__global__ void k_pack(const float* __restrict__ w0, const float* __restrict__ w1,
                       const float* __restrict__ w2, const float* __restrict__ w3,
                       const float* __restrict__ w4, unsigned short* __restrict__ Bp){
  int id = blockIdx.x * blockDim.x + threadIdx.x;
  if (id >= 5 * 2048) return;
  int mat = id >> 11, rem = id & 2047;
  int c = rem >> 8, q = (rem >> 6) & 3, l = rem & 63;
  const float* W = mat == 0 ? w0 : mat == 1 ? w1 : mat == 2 ? w2 : mat == 3 ? w3 : w4;
  unsigned short* o = Bp + ((size_t)mat * 2048 + rem) * 8;
  int kb = q * 32 + (l >> 4) * 8;
  int col = c * 16 + (l & 15);
  #pragma unroll
  for (int j = 0; j < 8; j++) o[j] = f2b(W[(kb + j) * 128 + col]);
}

// pack We[2][16][128] into K=32-padded B-fragments for mfma_f32_16x16x32_bf16:
// Bpwe[layer][c][lane][j] = bf16(We[k][c*16+(lane&15)]) for k=(lane>>4)*8+j < 16, else 0
__global__ void k_packwe(const float* __restrict__ We, unsigned short* __restrict__ Bpwe){
  int id = blockIdx.x * blockDim.x + threadIdx.x;
  if (id >= 2 * 8 * 64) return;
  int layer = id >> 9, rem = id & 511, c = rem >> 6, l = rem & 63;
  const float* W = We + (size_t)layer * 2048;     // [16][128]
  unsigned short* o = Bpwe + (size_t)id * 8;
  int kb = (l >> 4) * 8;
  int col = c * 16 + (l & 15);
  #pragma unroll
  for (int j = 0; j < 8; j++){
    int k = kb + j;
    o[j] = (k < 16) ? f2b(W[k * 128 + col]) : (unsigned short)0;
  }
}

// ---------------- MFMA GEMM: Y[M,128] = A[M,128](bf16) @ W + b ----------------
__launch_bounds__(256)
__global__ void k_mm(const unsigned short* __restrict__ A,
                     const unsigned short* __restrict__ Bp,
                     const float* __restrict__ bias,
                     unsigned short* __restrict__ Yb, int M){
  const int ln = threadIdx.x & 63;
  const int rowBase = (blockIdx.x * 4 + (threadIdx.x >> 6)) * 16;
  const int r16 = ln & 15, quad = ln >> 4;
  int row = rowBase + r16; if (row >= M) row = M - 1;
  const unsigned short* ap = A + (size_t)row * 128 + quad * 8;
  s16x8 af[4];
  #pragma unroll
  for (int q = 0; q < 4; q++) af[q] = *(const s16x8*)(ap + q * 32);
  f32x4 acc[8];
  #pragma unroll
  for (int c = 0; c < 8; c++){
    acc[c] = (f32x4){0.f, 0.f, 0.f, 0.f};
    #pragma unroll
    for (int q = 0; q < 4; q++){
      s16x8 bf = *(const s16x8*)(Bp + ((size_t)(c * 4 + q) * 64 + ln) * 8);
      acc[c] = __builtin_amdgcn_mfma_f32_16x16x32_bf16(af[q], bf, acc[c], 0, 0, 0);
    }
  }
  #pragma unroll
  for (int c = 0; c < 8; c++){
    int col = c * 16 + r16;
    float bv = bias[col];
    #pragma unroll
    for (int r = 0; r < 4; r++){
      int orow = rowBase + quad * 4 + r;
      if (orow < M) Yb[(size_t)orow * 128 + col] = f2b(acc[c][r] + bv);
    }
  }
}

// fused pair: YL = A@WL + bL ; YR = A@WR + bR  (fp32 outputs)
__launch_bounds__(256)
__global__ void k_mm_lr(const unsigned short* __restrict__ A,
                        const unsigned short* __restrict__ BpL,
                        const unsigned short* __restrict__ BpR,
                        const float* __restrict__ bL, const float* __restrict__ bR,
                        float* __restrict__ YL, float* __restrict__ YR, int M){
  const int ln = threadIdx.x & 63;
  const int rowBase = (blockIdx.x * 4 + (threadIdx.x >> 6)) * 16;
  const int r16 = ln & 15, quad = ln >> 4;
  int row = rowBase + r16; if (row >= M) row = M - 1;
  const unsigned short* ap = A + (size_t)row * 128 + quad * 8;
  s16x8 af[4];
  #pragma unroll
  for (int q = 0; q < 4; q++) af[q] = *(const s16x8*)(ap + q * 32);
  f32x4 aL[8], aR[8];
  #pragma unroll
  for (int c = 0; c < 8; c++){
    aL[c] = (f32x4){0.f, 0.f, 0.f, 0.f};
    aR[c] = (f32x4){0.f, 0.f, 0.f, 0.f};
    #pragma unroll
    for (int q = 0; q < 4; q++){
      s16x8 bfl = *(const s16x8*)(BpL + ((size_t)(c * 4 + q) * 64 + ln) * 8);
      s16x8 bfr = *(const s16x8*)(BpR + ((size_t)(c * 4 + q) * 64 + ln) * 8);
      aL[c] = __builtin_amdgcn_mfma_f32_16x16x32_bf16(af[q], bfl, aL[c], 0, 0, 0);
      aR[c] = __builtin_amdgcn_mfma_f32_16x16x32_bf16(af[q], bfr, aR[c], 0, 0, 0);
    }
  }
  #pragma unroll
  for (int c = 0; c < 8; c++){
    int col = c * 16 + r16;
    float bvl = bL[col], bvr = bR[col];
    #pragma unroll
    for (int r = 0; r < 4; r++){
      int orow = rowBase + quad * 4 + r;
      if (orow < M){
        YL[(size_t)orow * 128 + col] = aL[c][r] + bvl;
        YR[(size_t)orow * 128 + col] = aR[c][r] + bvr;
      }
    }
  }
}

// ---------------- Fused GAT layer ----------------
// Wave/node; lane t owns channels (2t,2t+1); head = t>>4.
// v4: ee = cea @ We on the matrix pipe.  A-fragment k-mapping FIXED:
//   for mfma_f32_16x16x32_bf16, lane (quad q, row l15) element j <-> k = q*8+j.
//   K=16 real features => quad 0 holds feat 0..7, quad 1 holds 8..15,
//   quads 2,3 all-zero (k_packwe zero-pads We rows 16..31 identically).
//   A-frag loaded in-loop (no runtime-indexed array -> no scratch).
//   C-frags scattered to LDS lee[edge][ch] stride 130 (2-way alias = free);
//   per-item consume = single ds_read_b64.
// Self loop via linearity: ee_self = (sum_e ee_e)/max(deg,1).
__launch_bounds__(256)
__global__ void k_gat(const float* __restrict__ xl, const float* __restrict__ xr,
                      const unsigned short* __restrict__ ceab,
                      const int* __restrict__ sx, const int* __restrict__ ptr,
                      const unsigned short* __restrict__ Bpwe,
                      const float* __restrict__ att, const float* __restrict__ cbv,
                      float* __restrict__ hf, unsigned short* __restrict__ hb,
                      int N, int wf, int wb){
  __shared__ float lee[4][16 * 130];     // [wave][edge*130 + ch], 33.3 KB
  const int t = threadIdx.x & 63;
  const int wv = threadIdx.x >> 6;
  const int c0 = 2 * t;
  const int l15 = t & 15, q = t >> 4;

  // We B-fragments (K=32, upper half zero) — loaded once, L2-cached
  s16x8 bwe[8];
  #pragma unroll
  for (int c = 0; c < 8; c++) bwe[c] = *(const s16x8*)(Bpwe + ((size_t)c * 64 + t) * 8);
  const f2 atv = *(const f2*)(att + c0);
  const f2 cbf = *(const f2*)(cbv + c0);
  float* lw = &lee[wv][0];
  const int wbase = q * 4 * 130 + l15;   // + r*130 + c*16 at write time

  for (int n = blockIdx.x * 4 + wv; n < N; n += gridDim.x * 4){
    const int beg = __builtin_amdgcn_readfirstlane(ptr[n]);
    const int end = __builtin_amdgcn_readfirstlane(ptr[n + 1]);
    const int deg = end - beg;

    const f2 xrv = *(const f2*)(xr + (size_t)n * 128 + c0);
    const f2 xln = *(const f2*)(xl + (size_t)n * 128 + c0);

    f2 acc = sp2(0.f), eesum = sp2(0.f);
    float den = 0.f;

    for (int cbase = beg; cbase < end; cbase += 64){
      const int cn = __builtin_amdgcn_readfirstlane(min(64, end - cbase));
      int sv = (t < cn) ? sx[cbase + t] : 0;

      for (int sub = 0; sub < cn; sub += 16){
        // A-fragment for this 16-edge tile: quad q element j <-> k=q*8+j.
        // Only quads 0,1 carry data (K=16); reads past cn hit ceab slack (masked).
        s16x8 af = (s16x8){0, 0, 0, 0, 0, 0, 0, 0};
        if (q < 2)
          af = *(const s16x8*)(ceab + (size_t)(cbase + sub + l15) * 16 + q * 8);
        // phase A: 16 independent xl gathers in flight
        f2 xs[16];
        #pragma unroll
        for (int i = 0; i < 16; i++){
          int s = __builtin_amdgcn_readlane(sv, sub + i);  // 0 for invalid slots
          xs[i] = *(const f2*)(xl + (size_t)s * 128 + c0);
        }
        // ee tile on the matrix pipe
        #pragma unroll
        for (int c = 0; c < 8; c++){
          f32x4 ee4 = __builtin_amdgcn_mfma_f32_16x16x32_bf16(
              af, bwe[c], (f32x4){0.f, 0.f, 0.f, 0.f}, 0, 0, 0);
          #pragma unroll
          for (int r = 0; r < 4; r++)
            lw[wbase + r * 130 + c * 16] = ee4[r];
        }
        // phase B: consume
        #pragma unroll
        for (int i = 0; i < 16; i++){
          const int item = sub + i;
          const float vm = (item < cn) ? 1.f : 0.f;
          const int it = (item < cn) ? i : 0;      // clamp: row 0 is valid data
          f2 ee = *(const f2*)&lw[it * 130 + c0];
          eesum = fma2(sp2(vm), ee, eesum);
          f2 m = xs[i] + xrv + ee;
          m = fma2(sp2(NEG_SLOPE), min2(m, sp2(0.f)), max2(m, sp2(0.f)));
          f2 pr = m * atv;
          float pl = pr.x + pr.y;
          pl += __shfl_xor(pl, 1); pl += __shfl_xor(pl, 2);
          pl += __shfl_xor(pl, 4); pl += __shfl_xor(pl, 8);
          float p = __expf(pl) * vm;
          den += p;
          acc = fma2(sp2(p), xs[i], acc);
        }
      }
    }

    // self loop: ee_self = eesum / max(deg,1)
    {
      float rdeg = 1.f / fmaxf((float)deg, 1.f);
      f2 m = xln + xrv + eesum * sp2(rdeg);
      m = fma2(sp2(NEG_SLOPE), min2(m, sp2(0.f)), max2(m, sp2(0.f)));
      f2 pr = m * atv;
      float pl = pr.x + pr.y;
      pl += __shfl_xor(pl, 1); pl += __shfl_xor(pl, 2);
      pl += __shfl_xor(pl, 4); pl += __shfl_xor(pl, 8);
      float p = __expf(pl);
      den += p;
      acc = fma2(sp2(p), xln, acc);
    }

    float rd = 1.f / den;
    f2 o = fma2(acc, sp2(rd), cbf);
    float o0 = o.x > 0.f ? o.x : expm1f(o.x);
    float o1 = o.y > 0.f ? o.y : expm1f(o.y);
    if (wf) *(f2*)(hf + (size_t)n * 128 + c0) = (f2){o0, o1};
    if (wb){
      unsigned packed = (unsigned)f2b(o0) | ((unsigned)f2b(o1) << 16);
      *(unsigned*)(hb + (size_t)n * 128 + c0) = packed;
    }
  }
}

// ---------------- LayerNorm + ReLU-MLP head ----------------
__launch_bounds__(256)
__global__ void k_head(const float* __restrict__ h, const float* __restrict__ g,
                       const float* __restrict__ b, const float* __restrict__ w1,
                       const float* __restrict__ b1, const float* __restrict__ w2,
                       const float* __restrict__ b2, float* __restrict__ out, int N){
  __shared__ float sn[4][128];
  const int t = threadIdx.x & 63, wv = threadIdx.x >> 6;
  for (int node = blockIdx.x * 4 + wv; node < N; node += gridDim.x * 4){
    float h0 = h[(size_t)node * 128 + t];
    float h1 = h[(size_t)node * 128 + 64 + t];
    float mu = wsum64(h0 + h1) * (1.f / 128.f);
    float d0 = h0 - mu, d1 = h1 - mu;
    float var = wsum64(d0 * d0 + d1 * d1) * (1.f / 128.f);
    float rstd = rsqrtf(var + LN_EPS);
    sn[wv][t]      = d0 * rstd * g[t]      + b[t];
    sn[wv][t + 64] = d1 * rstd * g[t + 64] + b[t + 64];
    float a = b1[t];
    #pragma unroll
    for (int k4 = 0; k4 < 32; k4++){
      float4 v = *(const float4*)&sn[wv][k4 * 4];
      a = fmaf(v.x, w1[(k4 * 4 + 0) * 64 + t], a);
      a = fmaf(v.y, w1[(k4 * 4 + 1) * 64 + t], a);
      a = fmaf(v.z, w1[(k4 * 4 + 2) * 64 + t], a);
      a = fmaf(v.w, w1[(k4 * 4 + 3) * 64 + t], a);
    }
    a = fmaxf(a, 0.f);
    float p0 = a * w2[t * 3 + 0], p1 = a * w2[t * 3 + 1], p2 = a * w2[t * 3 + 2];
    p0 = wsum64(p0); p1 = wsum64(p1); p2 = wsum64(p2);
    if (t == 0){
      out[(size_t)node * 3 + 0] = p0 + b2[0];
      out[(size_t)node * 3 + 1] = p1 + b2[1];
      out[(size_t)node * 3 + 2] = p2 + b2[2];
    }
  }
}

extern "C" void kernel_launch(void* const* d_in, const int* in_sizes, int n_in,
                              void* d_out, int out_size, void* d_ws, size_t ws_size,
                              hipStream_t stream){
  const float* x    = (const float*)d_in[0];
  const int*   ei   = (const int*)d_in[1];
  const float* ea   = (const float*)d_in[2];
  const float* in_w = (const float*)d_in[3];
  const float* in_b = (const float*)d_in[4];
  const float* Wl   = (const float*)d_in[5];
  const float* bl   = (const float*)d_in[6];
  const float* Wr   = (const float*)d_in[7];
  const float* br   = (const float*)d_in[8];
  const float* We   = (const float*)d_in[9];
  const float* att  = (const float*)d_in[10];
  const float* cb   = (const float*)d_in[11];
  const float* lng  = (const float*)d_in[12];
  const float* lnb  = (const float*)d_in[13];
  const float* h1w  = (const float*)d_in[14];
  const float* h1b  = (const float*)d_in[15];
  const float* h2w  = (const float*)d_in[16];
  const float* h2b  = (const float*)d_in[17];
  float* out = (float*)d_out;

  int N = in_sizes[0] / 128;
  int E = in_sizes[1] / 2;
  const int* src = ei;
  const int* dst = ei + E;

  char* w = (char*)d_ws;
  size_t off = 0;
  auto alloc = [&](size_t bytes) -> char* {
    char* p = w + off;
    off = (off + bytes + 255) & ~(size_t)255;
    return p;
  };
  int*   deg   = (int*)alloc((size_t)N * 4);
  int*   cnt   = (int*)alloc((size_t)N * 4);
  int*   ptr   = (int*)alloc((size_t)(N + 1) * 4);
  int*   bsum  = (int*)alloc(256 * 4);
  int*   sx    = (int*)alloc((size_t)E * 4);
  unsigned short* ceab = (unsigned short*)alloc((size_t)(E + 64) * 16 * 2); // bf16 CSR edge_attr (+slack)
  unsigned short* xb    = (unsigned short*)alloc((size_t)N * 128 * 2);  // layer-0 gat bf16 out
  unsigned short* hb_in = (unsigned short*)alloc((size_t)N * 128 * 2);
  unsigned short* Bp    = (unsigned short*)alloc((size_t)5 * 16384 * 2);
  unsigned short* Bpwe  = (unsigned short*)alloc((size_t)2 * 4096 * 2);  // We K=32-padded frags
  float* hf    = (float*)alloc((size_t)N * 128 * 4);
  float* xlb   = (float*)alloc((size_t)N * 128 * 4);
  float* xrb   = (float*)alloc((size_t)N * 128 * 4);

  int nb = (N + 255) / 256;
  hipMemsetAsync(deg, 0, (size_t)N * 4, stream);
  hipMemsetAsync(cnt, 0, (size_t)N * 4, stream);
  k_count<<<(E + 255) / 256, 256, 0, stream>>>(dst, deg, E);
  k_scan_blk<<<nb, 256, 0, stream>>>(deg, ptr, bsum, N);
  k_scan_top<<<1, 256, 0, stream>>>(bsum, nb);
  k_scan_add<<<nb, 256, 0, stream>>>(ptr, bsum, N, E);
  k_fill<<<(E + 255) / 256, 256, 0, stream>>>(dst, src, cnt, ptr, ea, ceab, sx, E);

  long n4 = (long)N * 128;
  k_cvt<<<(int)((n4 / 4 + 255) / 256), 256, 0, stream>>>(x, xb, n4);
  k_pack<<<(5 * 2048 + 255) / 256, 256, 0, stream>>>(in_w, Wl, Wl + 16384, Wr, Wr + 16384, Bp);
  k_packwe<<<4, 256, 0, stream>>>(We, Bpwe);

  int gblocks = (N + 63) / 64;
  int nodeBlocks = (N + 3) / 4;
  int gatBlocks = nodeBlocks < 2048 ? nodeBlocks : 2048;
  // in-proj: h = x @ in_w + in_b  (bf16 out)
  k_mm<<<gblocks, 256, 0, stream>>>(xb, Bp, in_b, hb_in, N);
  for (int l = 0; l < 2; l++){
    const unsigned short* Ain = (l == 0) ? hb_in : xb;  // layer-0 gat writes bf16 into xb
    k_mm_lr<<<gblocks, 256, 0, stream>>>(Ain, Bp + (size_t)(1 + l) * 16384,
                                         Bp + (size_t)(3 + l) * 16384,
                                         bl + l * 128, br + l * 128, xlb, xrb, N);
    k_gat<<<gatBlocks, 256, 0, stream>>>(xlb, xrb, ceab, sx, ptr,
                                         Bpwe + (size_t)l * 4096,
                                         att + l * 128, cb + l * 128,
                                         hf, xb, N, (l == 1) ? 1 : 0, (l == 0) ? 1 : 0);
  }
  k_head<<<gatBlocks, 256, 0, stream>>>(hf, lng, lnb, h1w, h1b, h2w, h2b, out, N);
}

// Round 7
// 486.443 us; speedup vs baseline: 1.2201x; 1.0435x over previous
//
#include <hip/hip_runtime.h>

#define NEG_SLOPE 0.2f
#define LN_EPS 1e-5f

typedef float f2 __attribute__((ext_vector_type(2)));
typedef short s16x4 __attribute__((ext_vector_type(4)));
typedef short s16x8 __attribute__((ext_vector_type(8)));
typedef float f32x4 __attribute__((ext_vector_type(4)));
typedef unsigned au32 __attribute__((may_alias));   // TBAA-safe LDS pair read

__device__ __forceinline__ f2 sp2(float x){ return (f2){x, x}; }
__device__ __forceinline__ f2 fma2(f2 a, f2 b, f2 c){
#if __has_builtin(__builtin_elementwise_fma)
  return __builtin_elementwise_fma(a, b, c);
#else
  f2 r; r.x = fmaf(a.x, b.x, c.x); r.y = fmaf(a.y, b.y, c.y); return r;
#endif
}
__device__ __forceinline__ f2 max2(f2 a, f2 b){
#if __has_builtin(__builtin_elementwise_max)
  return __builtin_elementwise_max(a, b);
#else
  f2 r; r.x = fmaxf(a.x, b.x); r.y = fmaxf(a.y, b.y); return r;
#endif
}
__device__ __forceinline__ f2 min2(f2 a, f2 b){
#if __has_builtin(__builtin_elementwise_min)
  return __builtin_elementwise_min(a, b);
#else
  f2 r; r.x = fminf(a.x, b.x); r.y = fminf(a.y, b.y); return r;
#endif
}
__device__ __forceinline__ float wsum64(float v){
  #pragma unroll
  for (int o = 32; o >= 1; o >>= 1) v += __shfl_xor(v, o);
  return v;
}
// fp32 -> bf16 round-nearest-even
__device__ __forceinline__ unsigned short f2b(float f){
  unsigned u = __float_as_uint(f);
  return (unsigned short)((u + 0x7fffu + ((u >> 16) & 1u)) >> 16);
}

// ---------------- CSR build ----------------
__global__ void k_count(const int* __restrict__ dst, int* __restrict__ deg, int E){
  int e = blockIdx.x * blockDim.x + threadIdx.x;
  if (e < E) atomicAdd(&deg[dst[e]], 1);
}

__global__ void k_scan_blk(const int* __restrict__ deg, int* __restrict__ part,
                           int* __restrict__ sums, int n){
  __shared__ int buf[256];
  int t = threadIdx.x, i = blockIdx.x * 256 + t;
  int v = (i < n) ? deg[i] : 0;
  buf[t] = v; __syncthreads();
  #pragma unroll
  for (int off = 1; off < 256; off <<= 1){
    int x = (t >= off) ? buf[t - off] : 0;
    __syncthreads(); buf[t] += x; __syncthreads();
  }
  if (i < n) part[i] = buf[t] - v;
  if (t == 255) sums[blockIdx.x] = buf[255];
}

__global__ void k_scan_top(int* __restrict__ sums, int nb){
  __shared__ int buf[256];
  int t = threadIdx.x;
  int v = (t < nb) ? sums[t] : 0;
  buf[t] = v; __syncthreads();
  #pragma unroll
  for (int off = 1; off < 256; off <<= 1){
    int x = (t >= off) ? buf[t - off] : 0;
    __syncthreads(); buf[t] += x; __syncthreads();
  }
  if (t < nb) sums[t] = buf[t] - v;
}

__global__ void k_scan_add(int* __restrict__ ptr, const int* __restrict__ sums,
                           int n, int Etot){
  int i = blockIdx.x * 256 + threadIdx.x;
  if (i < n) ptr[i] += sums[blockIdx.x];
  if (i == 0) ptr[n] = Etot;
}

// CSR fill: scatter src + edge_attr row (converted to bf16) into CSR order.
// ceab is [E+64][16] bf16 row-major (32B/row) -> feeds MFMA A-fragments in k_gat.
__global__ void k_fill(const int* __restrict__ dst, const int* __restrict__ src,
                       int* __restrict__ cnt, const int* __restrict__ ptr,
                       const float* __restrict__ ea, unsigned short* __restrict__ ceab,
                       int* __restrict__ sx, int E){
  int e = blockIdx.x * blockDim.x + threadIdx.x;
  if (e < E){
    int d = dst[e];
    int pos = atomicAdd(&cnt[d], 1);
    int p = ptr[d] + pos;
    sx[p] = src[e];
    const float4* s4 = (const float4*)(ea + (size_t)e * 16);
    float4 a0 = s4[0], a1 = s4[1], a2 = s4[2], a3 = s4[3];
    ushort4 o0 = {f2b(a0.x), f2b(a0.y), f2b(a0.z), f2b(a0.w)};
    ushort4 o1 = {f2b(a1.x), f2b(a1.y), f2b(a1.z), f2b(a1.w)};
    ushort4 o2 = {f2b(a2.x), f2b(a2.y), f2b(a2.z), f2b(a2.w)};
    ushort4 o3 = {f2b(a3.x), f2b(a3.y), f2b(a3.z), f2b(a3.w)};
    ushort4* d4 = (ushort4*)(ceab + (size_t)p * 16);
    d4[0] = o0; d4[1] = o1; d4[2] = o2; d4[3] = o3;
  }
}

// ---------------- bf16 convert + B-fragment pack ----------------
__global__ void k_cvt(const float* __restrict__ X, unsigned short* __restrict__ Xb,
                      long n4){
  long i = (long)blockIdx.x * blockDim.x + threadIdx.x;
  long i4 = i * 4;
  if (i4 < n4){
    float4 v = *(const float4*)(X + i4);
    ushort4 o; o.x = f2b(v.x); o.y = f2b(v.y); o.z = f2b(v.z); o.w = f2b(v.w);
    *(ushort4*)(Xb + i4) = o;
  }
}

// pack 5 [128,128] row-major fp32 matrices into MFMA B-fragment order:
// Bp[mat][c][q][lane][j] = bf16(W[q*32 + (lane>>4)*8 + j][c*16 + (lane&15)])
__global__ void k_pack(const float* __restrict__ w0, const float* __restrict__ w1,
                       const float* __restrict__ w2, const float* __restrict__ w3,
                       const float* __restrict__ w4, unsigned short* __restrict__ Bp){
  int id = blockIdx.x * blockDim.x + threadIdx.x;
  if (id >= 5 * 2048) return;
  int mat = id >> 11, rem = id & 2047;
  int c = rem >> 8, q = (rem >> 6) & 3, l = rem & 63;
  const float* W = mat == 0 ? w0 : mat == 1 ? w1 : mat == 2 ? w2 : mat == 3 ? w3 : w4;
  unsigned short* o = Bp + ((size_t)mat * 2048 + rem) * 8;
  int kb = q * 32 + (l >> 4) * 8;
  int col = c * 16 + (l & 15);
  #pragma unroll
  for (int j = 0; j < 8; j++) o[j] = f2b(W[(kb + j) * 128 + col]);
}

// pack We[2][16][128] into K=32-padded B-fragments for mfma_f32_16x16x32_bf16:
// Bpwe[layer][c][lane][j] = bf16(We[k][c*16+(lane&15)]) for k=(lane>>4)*8+j < 16, else 0
__global__ void k_packwe(const float* __restrict__ We, unsigned short* __restrict__ Bpwe){
  int id = blockIdx.x * blockDim.x + threadIdx.x;
  if (id >= 2 * 8 * 64) return;
  int layer = id >> 9, rem = id & 511, c = rem >> 6, l = rem & 63;
  const float* W = We + (size_t)layer * 2048;     // [16][128]
  unsigned short* o = Bpwe + (size_t)id * 8;
  int kb = (l >> 4) * 8;
  int col = c * 16 + (l & 15);
  #pragma unroll
  for (int j = 0; j < 8; j++){
    int k = kb + j;
    o[j] = (k < 16) ? f2b(W[k * 128 + col]) : (unsigned short)0;
  }
}

// ---------------- MFMA GEMM: Y[M,128] = A[M,128](bf16) @ W + b ----------------
__launch_bounds__(256)
__global__ void k_mm(const unsigned short* __restrict__ A,
                     const unsigned short* __restrict__ Bp,
                     const float* __restrict__ bias,
                     unsigned short* __restrict__ Yb, int M){
  const int ln = threadIdx.x & 63;
  const int rowBase = (blockIdx.x * 4 + (threadIdx.x >> 6)) * 16;
  const int r16 = ln & 15, quad = ln >> 4;
  int row = rowBase + r16; if (row >= M) row = M - 1;
  const unsigned short* ap = A + (size_t)row * 128 + quad * 8;
  s16x8 af[4];
  #pragma unroll
  for (int q = 0; q < 4; q++) af[q] = *(const s16x8*)(ap + q * 32);
  f32x4 acc[8];
  #pragma unroll
  for (int c = 0; c < 8; c++){
    acc[c] = (f32x4){0.f, 0.f, 0.f, 0.f};
    #pragma unroll
    for (int q = 0; q < 4; q++){
      s16x8 bf = *(const s16x8*)(Bp + ((size_t)(c * 4 + q) * 64 + ln) * 8);
      acc[c] = __builtin_amdgcn_mfma_f32_16x16x32_bf16(af[q], bf, acc[c], 0, 0, 0);
    }
  }
  #pragma unroll
  for (int c = 0; c < 8; c++){
    int col = c * 16 + r16;
    float bv = bias[col];
    #pragma unroll
    for (int r = 0; r < 4; r++){
      int orow = rowBase + quad * 4 + r;
      if (orow < M) Yb[(size_t)orow * 128 + col] = f2b(acc[c][r] + bv);
    }
  }
}

// fused pair: YL = A@WL + bL ; YR = A@WR + bR  (fp32 outputs)
__launch_bounds__(256)
__global__ void k_mm_lr(const unsigned short* __restrict__ A,
                        const unsigned short* __restrict__ BpL,
                        const unsigned short* __restrict__ BpR,
                        const float* __restrict__ bL, const float* __restrict__ bR,
                        float* __restrict__ YL, float* __restrict__ YR, int M){
  const int ln = threadIdx.x & 63;
  const int rowBase = (blockIdx.x * 4 + (threadIdx.x >> 6)) * 16;
  const int r16 = ln & 15, quad = ln >> 4;
  int row = rowBase + r16; if (row >= M) row = M - 1;
  const unsigned short* ap = A + (size_t)row * 128 + quad * 8;
  s16x8 af[4];
  #pragma unroll
  for (int q = 0; q < 4; q++) af[q] = *(const s16x8*)(ap + q * 32);
  f32x4 aL[8], aR[8];
  #pragma unroll
  for (int c = 0; c < 8; c++){
    aL[c] = (f32x4){0.f, 0.f, 0.f, 0.f};
    aR[c] = (f32x4){0.f, 0.f, 0.f, 0.f};
    #pragma unroll
    for (int q = 0; q < 4; q++){
      s16x8 bfl = *(const s16x8*)(BpL + ((size_t)(c * 4 + q) * 64 + ln) * 8);
      s16x8 bfr = *(const s16x8*)(BpR + ((size_t)(c * 4 + q) * 64 + ln) * 8);
      aL[c] = __builtin_amdgcn_mfma_f32_16x16x32_bf16(af[q], bfl, aL[c], 0, 0, 0);
      aR[c] = __builtin_amdgcn_mfma_f32_16x16x32_bf16(af[q], bfr, aR[c], 0, 0, 0);
    }
  }
  #pragma unroll
  for (int c = 0; c < 8; c++){
    int col = c * 16 + r16;
    float bvl = bL[col], bvr = bR[col];
    #pragma unroll
    for (int r = 0; r < 4; r++){
      int orow = rowBase + quad * 4 + r;
      if (orow < M){
        YL[(size_t)orow * 128 + col] = aL[c][r] + bvl;
        YR[(size_t)orow * 128 + col] = aR[c][r] + bvr;
      }
    }
  }
}

// ---------------- Fused GAT layer ----------------
// Wave/node; lane t owns channels (2t,2t+1); head = t>>4.
// v6 = v5 (bf16 ee tile in LDS, 16.25 KB/block -> 8 blocks/CU occupancy cap)
//      + may_alias fix: v5 read the ushort-stored tile through unsigned*,
//      TBAA said no-alias -> backend reordered ds_read vs ds_write -> stale
//      ee (absmax 0.68). au32 (may_alias) restores ordering, keeps 1x b32 read.
// Self loop via linearity: ee_self = (sum_e ee_e)/max(deg,1).
__launch_bounds__(256)
__global__ void k_gat(const float* __restrict__ xl, const float* __restrict__ xr,
                      const unsigned short* __restrict__ ceab,
                      const int* __restrict__ sx, const int* __restrict__ ptr,
                      const unsigned short* __restrict__ Bpwe,
                      const float* __restrict__ att, const float* __restrict__ cbv,
                      float* __restrict__ hf, unsigned short* __restrict__ hb,
                      int N, int wf, int wb){
  __shared__ unsigned short lee[4][16 * 130];   // bf16 ee, 16.25 KB total
  const int t = threadIdx.x & 63;
  const int wv = threadIdx.x >> 6;
  const int c0 = 2 * t;
  const int l15 = t & 15, q = t >> 4;

  // We B-fragments (K=32, upper half zero) — loaded once, L2-cached
  s16x8 bwe[8];
  #pragma unroll
  for (int c = 0; c < 8; c++) bwe[c] = *(const s16x8*)(Bpwe + ((size_t)c * 64 + t) * 8);
  const f2 atv = *(const f2*)(att + c0);
  const f2 cbf = *(const f2*)(cbv + c0);
  unsigned short* lw = &lee[wv][0];
  const int wbase = q * 4 * 130 + l15;   // + r*130 + c*16 at write time

  for (int n = blockIdx.x * 4 + wv; n < N; n += gridDim.x * 4){
    const int beg = __builtin_amdgcn_readfirstlane(ptr[n]);
    const int end = __builtin_amdgcn_readfirstlane(ptr[n + 1]);
    const int deg = end - beg;

    const f2 xrv = *(const f2*)(xr + (size_t)n * 128 + c0);
    const f2 xln = *(const f2*)(xl + (size_t)n * 128 + c0);

    f2 acc = sp2(0.f), eesum = sp2(0.f);
    float den = 0.f;

    for (int cbase = beg; cbase < end; cbase += 64){
      const int cn = __builtin_amdgcn_readfirstlane(min(64, end - cbase));
      int sv = (t < cn) ? sx[cbase + t] : 0;

      for (int sub = 0; sub < cn; sub += 16){
        // A-fragment for this 16-edge tile: quad q element j <-> k=q*8+j.
        // Only quads 0,1 carry data (K=16); reads past cn hit ceab slack (masked).
        s16x8 af = (s16x8){0, 0, 0, 0, 0, 0, 0, 0};
        if (q < 2)
          af = *(const s16x8*)(ceab + (size_t)(cbase + sub + l15) * 16 + q * 8);
        // phase A: 16 independent xl gathers in flight
        f2 xs[16];
        #pragma unroll
        for (int i = 0; i < 16; i++){
          int s = __builtin_amdgcn_readlane(sv, sub + i);  // 0 for invalid slots
          xs[i] = *(const f2*)(xl + (size_t)s * 128 + c0);
        }
        // ee tile on the matrix pipe; scatter C-frags to LDS as bf16
        #pragma unroll
        for (int c = 0; c < 8; c++){
          f32x4 ee4 = __builtin_amdgcn_mfma_f32_16x16x32_bf16(
              af, bwe[c], (f32x4){0.f, 0.f, 0.f, 0.f}, 0, 0, 0);
          #pragma unroll
          for (int r = 0; r < 4; r++)
            lw[wbase + r * 130 + c * 16] = f2b(ee4[r]);
        }
        // phase B: consume (1x ds_read_b32 = the lane's bf16 col-pair)
        #pragma unroll
        for (int i = 0; i < 16; i++){
          const int item = sub + i;
          const float vm = (item < cn) ? 1.f : 0.f;
          const int it = (item < cn) ? i : 0;      // clamp: row 0 is valid data
          au32 pp = *(const au32*)&lw[it * 130 + c0];
          f2 ee;
          ee.x = __uint_as_float(pp << 16);
          ee.y = __uint_as_float(pp & 0xffff0000u);
          eesum = fma2(sp2(vm), ee, eesum);
          f2 m = xs[i] + xrv + ee;
          m = fma2(sp2(NEG_SLOPE), min2(m, sp2(0.f)), max2(m, sp2(0.f)));
          f2 pr = m * atv;
          float pl = pr.x + pr.y;
          pl += __shfl_xor(pl, 1); pl += __shfl_xor(pl, 2);
          pl += __shfl_xor(pl, 4); pl += __shfl_xor(pl, 8);
          float p = __expf(pl) * vm;
          den += p;
          acc = fma2(sp2(p), xs[i], acc);
        }
      }
    }

    // self loop: ee_self = eesum / max(deg,1)
    {
      float rdeg = 1.f / fmaxf((float)deg, 1.f);
      f2 m = xln + xrv + eesum * sp2(rdeg);
      m = fma2(sp2(NEG_SLOPE), min2(m, sp2(0.f)), max2(m, sp2(0.f)));
      f2 pr = m * atv;
      float pl = pr.x + pr.y;
      pl += __shfl_xor(pl, 1); pl += __shfl_xor(pl, 2);
      pl += __shfl_xor(pl, 4); pl += __shfl_xor(pl, 8);
      float p = __expf(pl);
      den += p;
      acc = fma2(sp2(p), xln, acc);
    }

    float rd = 1.f / den;
    f2 o = fma2(acc, sp2(rd), cbf);
    float o0 = o.x > 0.f ? o.x : expm1f(o.x);
    float o1 = o.y > 0.f ? o.y : expm1f(o.y);
    if (wf) *(f2*)(hf + (size_t)n * 128 + c0) = (f2){o0, o1};
    if (wb){
      unsigned packed = (unsigned)f2b(o0) | ((unsigned)f2b(o1) << 16);
      *(unsigned*)(hb + (size_t)n * 128 + c0) = packed;
    }
  }
}

// ---------------- LayerNorm + ReLU-MLP head ----------------
__launch_bounds__(256)
__global__ void k_head(const float* __restrict__ h, const float* __restrict__ g,
                       const float* __restrict__ b, const float* __restrict__ w1,
                       const float* __restrict__ b1, const float* __restrict__ w2,
                       const float* __restrict__ b2, float* __restrict__ out, int N){
  __shared__ float sn[4][128];
  const int t = threadIdx.x & 63, wv = threadIdx.x >> 6;
  for (int node = blockIdx.x * 4 + wv; node < N; node += gridDim.x * 4){
    float h0 = h[(size_t)node * 128 + t];
    float h1 = h[(size_t)node * 128 + 64 + t];
    float mu = wsum64(h0 + h1) * (1.f / 128.f);
    float d0 = h0 - mu, d1 = h1 - mu;
    float var = wsum64(d0 * d0 + d1 * d1) * (1.f / 128.f);
    float rstd = rsqrtf(var + LN_EPS);
    sn[wv][t]      = d0 * rstd * g[t]      + b[t];
    sn[wv][t + 64] = d1 * rstd * g[t + 64] + b[t + 64];
    float a = b1[t];
    #pragma unroll
    for (int k4 = 0; k4 < 32; k4++){
      float4 v = *(const float4*)&sn[wv][k4 * 4];
      a = fmaf(v.x, w1[(k4 * 4 + 0) * 64 + t], a);
      a = fmaf(v.y, w1[(k4 * 4 + 1) * 64 + t], a);
      a = fmaf(v.z, w1[(k4 * 4 + 2) * 64 + t], a);
      a = fmaf(v.w, w1[(k4 * 4 + 3) * 64 + t], a);
    }
    a = fmaxf(a, 0.f);
    float p0 = a * w2[t * 3 + 0], p1 = a * w2[t * 3 + 1], p2 = a * w2[t * 3 + 2];
    p0 = wsum64(p0); p1 = wsum64(p1); p2 = wsum64(p2);
    if (t == 0){
      out[(size_t)node * 3 + 0] = p0 + b2[0];
      out[(size_t)node * 3 + 1] = p1 + b2[1];
      out[(size_t)node * 3 + 2] = p2 + b2[2];
    }
  }
}

extern "C" void kernel_launch(void* const* d_in, const int* in_sizes, int n_in,
                              void* d_out, int out_size, void* d_ws, size_t ws_size,
                              hipStream_t stream){
  const float* x    = (const float*)d_in[0];
  const int*   ei   = (const int*)d_in[1];
  const float* ea   = (const float*)d_in[2];
  const float* in_w = (const float*)d_in[3];
  const float* in_b = (const float*)d_in[4];
  const float* Wl   = (const float*)d_in[5];
  const float* bl   = (const float*)d_in[6];
  const float* Wr   = (const float*)d_in[7];
  const float* br   = (const float*)d_in[8];
  const float* We   = (const float*)d_in[9];
  const float* att  = (const float*)d_in[10];
  const float* cb   = (const float*)d_in[11];
  const float* lng  = (const float*)d_in[12];
  const float* lnb  = (const float*)d_in[13];
  const float* h1w  = (const float*)d_in[14];
  const float* h1b  = (const float*)d_in[15];
  const float* h2w  = (const float*)d_in[16];
  const float* h2b  = (const float*)d_in[17];
  float* out = (float*)d_out;

  int N = in_sizes[0] / 128;
  int E = in_sizes[1] / 2;
  const int* src = ei;
  const int* dst = ei + E;

  char* w = (char*)d_ws;
  size_t off = 0;
  auto alloc = [&](size_t bytes) -> char* {
    char* p = w + off;
    off = (off + bytes + 255) & ~(size_t)255;
    return p;
  };
  int*   deg   = (int*)alloc((size_t)N * 4);
  int*   cnt   = (int*)alloc((size_t)N * 4);
  int*   ptr   = (int*)alloc((size_t)(N + 1) * 4);
  int*   bsum  = (int*)alloc(256 * 4);
  int*   sx    = (int*)alloc((size_t)E * 4);
  unsigned short* ceab = (unsigned short*)alloc((size_t)(E + 64) * 16 * 2); // bf16 CSR edge_attr (+slack)
  unsigned short* xb    = (unsigned short*)alloc((size_t)N * 128 * 2);  // layer-0 gat bf16 out
  unsigned short* hb_in = (unsigned short*)alloc((size_t)N * 128 * 2);
  unsigned short* Bp    = (unsigned short*)alloc((size_t)5 * 16384 * 2);
  unsigned short* Bpwe  = (unsigned short*)alloc((size_t)2 * 4096 * 2);  // We K=32-padded frags
  float* hf    = (float*)alloc((size_t)N * 128 * 4);
  float* xlb   = (float*)alloc((size_t)N * 128 * 4);
  float* xrb   = (float*)alloc((size_t)N * 128 * 4);

  int nb = (N + 255) / 256;
  hipMemsetAsync(deg, 0, (size_t)N * 4, stream);
  hipMemsetAsync(cnt, 0, (size_t)N * 4, stream);
  k_count<<<(E + 255) / 256, 256, 0, stream>>>(dst, deg, E);
  k_scan_blk<<<nb, 256, 0, stream>>>(deg, ptr, bsum, N);
  k_scan_top<<<1, 256, 0, stream>>>(bsum, nb);
  k_scan_add<<<nb, 256, 0, stream>>>(ptr, bsum, N, E);
  k_fill<<<(E + 255) / 256, 256, 0, stream>>>(dst, src, cnt, ptr, ea, ceab, sx, E);

  long n4 = (long)N * 128;
  k_cvt<<<(int)((n4 / 4 + 255) / 256), 256, 0, stream>>>(x, xb, n4);
  k_pack<<<(5 * 2048 + 255) / 256, 256, 0, stream>>>(in_w, Wl, Wl + 16384, Wr, Wr + 16384, Bp);
  k_packwe<<<4, 256, 0, stream>>>(We, Bpwe);

  int gblocks = (N + 63) / 64;
  int nodeBlocks = (N + 3) / 4;
  int gatBlocks = nodeBlocks < 2048 ? nodeBlocks : 2048;
  // in-proj: h = x @ in_w + in_b  (bf16 out)
  k_mm<<<gblocks, 256, 0, stream>>>(xb, Bp, in_b, hb_in, N);
  for (int l = 0; l < 2; l++){
    const unsigned short* Ain = (l == 0) ? hb_in : xb;  // layer-0 gat writes bf16 into xb
    k_mm_lr<<<gblocks, 256, 0, stream>>>(Ain, Bp + (size_t)(1 + l) * 16384,
                                         Bp + (size_t)(3 + l) * 16384,
                                         bl + l * 128, br + l * 128, xlb, xrb, N);
    k_gat<<<gatBlocks, 256, 0, stream>>>(xlb, xrb, ceab, sx, ptr,
                                         Bpwe + (size_t)l * 4096,
                                         att + l * 128, cb + l * 128,
                                         hf, xb, N, (l == 1) ? 1 : 0, (l == 0) ? 1 : 0);
  }
  k_head<<<gatBlocks, 256, 0, stream>>>(hf, lng, lnb, h1w, h1b, h2w, h2b, out, N);
}

// Round 8
// 471.260 us; speedup vs baseline: 1.2594x; 1.0322x over previous
//
#include <hip/hip_runtime.h>

#define NEG_SLOPE 0.2f
#define LN_EPS 1e-5f

typedef float f2 __attribute__((ext_vector_type(2)));
typedef short s16x8 __attribute__((ext_vector_type(8)));
typedef float f32x4 __attribute__((ext_vector_type(4)));
typedef unsigned au32 __attribute__((may_alias));   // TBAA-safe bf16-pair read

__device__ __forceinline__ f2 sp2(float x){ return (f2){x, x}; }
__device__ __forceinline__ f2 fma2(f2 a, f2 b, f2 c){
#if __has_builtin(__builtin_elementwise_fma)
  return __builtin_elementwise_fma(a, b, c);
#else
  f2 r; r.x = fmaf(a.x, b.x, c.x); r.y = fmaf(a.y, b.y, c.y); return r;
#endif
}
__device__ __forceinline__ f2 max2(f2 a, f2 b){
#if __has_builtin(__builtin_elementwise_max)
  return __builtin_elementwise_max(a, b);
#else
  f2 r; r.x = fmaxf(a.x, b.x); r.y = fmaxf(a.y, b.y); return r;
#endif
}
__device__ __forceinline__ f2 min2(f2 a, f2 b){
#if __has_builtin(__builtin_elementwise_min)
  return __builtin_elementwise_min(a, b);
#else
  f2 r; r.x = fminf(a.x, b.x); r.y = fminf(a.y, b.y); return r;
#endif
}
__device__ __forceinline__ float wsum64(float v){
  #pragma unroll
  for (int o = 32; o >= 1; o >>= 1) v += __shfl_xor(v, o);
  return v;
}
// fp32 -> bf16 round-nearest-even
__device__ __forceinline__ unsigned short f2b(float f){
  unsigned u = __float_as_uint(f);
  return (unsigned short)((u + 0x7fffu + ((u >> 16) & 1u)) >> 16);
}
// unpack bf16 pair (u32) -> f2, exact
__device__ __forceinline__ f2 b2f2(unsigned pp){
  f2 r;
  r.x = __uint_as_float(pp << 16);
  r.y = __uint_as_float(pp & 0xffff0000u);
  return r;
}

// ---------------- CSR build ----------------
__global__ void k_count(const int* __restrict__ dst, int* __restrict__ deg, int E){
  int e = blockIdx.x * blockDim.x + threadIdx.x;
  if (e < E) atomicAdd(&deg[dst[e]], 1);
}

__global__ void k_scan_blk(const int* __restrict__ deg, int* __restrict__ part,
                           int* __restrict__ sums, int n){
  __shared__ int buf[256];
  int t = threadIdx.x, i = blockIdx.x * 256 + t;
  int v = (i < n) ? deg[i] : 0;
  buf[t] = v; __syncthreads();
  #pragma unroll
  for (int off = 1; off < 256; off <<= 1){
    int x = (t >= off) ? buf[t - off] : 0;
    __syncthreads(); buf[t] += x; __syncthreads();
  }
  if (i < n) part[i] = buf[t] - v;
  if (t == 255) sums[blockIdx.x] = buf[255];
}

__global__ void k_scan_top(int* __restrict__ sums, int nb){
  __shared__ int buf[256];
  int t = threadIdx.x;
  int v = (t < nb) ? sums[t] : 0;
  buf[t] = v; __syncthreads();
  #pragma unroll
  for (int off = 1; off < 256; off <<= 1){
    int x = (t >= off) ? buf[t - off] : 0;
    __syncthreads(); buf[t] += x; __syncthreads();
  }
  if (t < nb) sums[t] = buf[t] - v;
}

__global__ void k_scan_add(int* __restrict__ ptr, const int* __restrict__ sums,
                           int n, int Etot){
  int i = blockIdx.x * 256 + threadIdx.x;
  if (i < n) ptr[i] += sums[blockIdx.x];
  if (i == 0) ptr[n] = Etot;
}

// CSR fill: scatter src + edge_attr row (converted to bf16) into CSR order.
// ceab is [E+64][16] bf16 row-major (32B/row) -> feeds MFMA A-fragments in k_gat.
__global__ void k_fill(const int* __restrict__ dst, const int* __restrict__ src,
                       int* __restrict__ cnt, const int* __restrict__ ptr,
                       const float* __restrict__ ea, unsigned short* __restrict__ ceab,
                       int* __restrict__ sx, int E){
  int e = blockIdx.x * blockDim.x + threadIdx.x;
  if (e < E){
    int d = dst[e];
    int pos = atomicAdd(&cnt[d], 1);
    int p = ptr[d] + pos;
    sx[p] = src[e];
    const float4* s4 = (const float4*)(ea + (size_t)e * 16);
    float4 a0 = s4[0], a1 = s4[1], a2 = s4[2], a3 = s4[3];
    ushort4 o0 = {f2b(a0.x), f2b(a0.y), f2b(a0.z), f2b(a0.w)};
    ushort4 o1 = {f2b(a1.x), f2b(a1.y), f2b(a1.z), f2b(a1.w)};
    ushort4 o2 = {f2b(a2.x), f2b(a2.y), f2b(a2.z), f2b(a2.w)};
    ushort4 o3 = {f2b(a3.x), f2b(a3.y), f2b(a3.z), f2b(a3.w)};
    ushort4* d4 = (ushort4*)(ceab + (size_t)p * 16);
    d4[0] = o0; d4[1] = o1; d4[2] = o2; d4[3] = o3;
  }
}

// ---------------- weight fold: Wc = in_w @ W0, bc = in_b @ W0 + b0 ----------------
// Exact linearity: h = x@in_w + in_b feeds ONLY layer-0 projections, so
// xl0 = x@(in_w@Wl0) + (in_b@Wl0 + bl0)  — eliminates the M=50000 in-proj GEMM.
__global__ void k_fold(const float* __restrict__ in_w, const float* __restrict__ in_b,
                       const float* __restrict__ Wl0, const float* __restrict__ bl0,
                       const float* __restrict__ Wr0, const float* __restrict__ br0,
                       float* __restrict__ Wcl, float* __restrict__ bcl,
                       float* __restrict__ Wcr, float* __restrict__ bcr){
  int id = blockIdx.x * blockDim.x + threadIdx.x;
  if (id < 2 * 16384){
    int m = id >> 14, rem = id & 16383;
    int k = rem >> 7, c = rem & 127;
    const float* W = m ? Wr0 : Wl0;
    float s = 0.f;
    #pragma unroll 4
    for (int d = 0; d < 128; d++) s = fmaf(in_w[k * 128 + d], W[d * 128 + c], s);
    (m ? Wcr : Wcl)[k * 128 + c] = s;
  } else if (id < 2 * 16384 + 256){
    int id2 = id - 2 * 16384;
    int m = id2 >> 7, c = id2 & 127;
    const float* W = m ? Wr0 : Wl0;
    float s = (m ? br0 : bl0)[c];
    for (int d = 0; d < 128; d++) s = fmaf(in_b[d], W[d * 128 + c], s);
    (m ? bcr : bcl)[c] = s;
  }
}

// ---------------- fused prep: cvt x->bf16, zero deg/cnt, pack 4 W mats, pack We ----
// Bp mats: 0=Wcl(L0 left) 1=Wl1 2=Wcr(L0 right) 3=Wr1
// Bp[mat][c][q][lane][j] = bf16(W[q*32+(lane>>4)*8+j][c*16+(lane&15)])
// Bpwe[layer][c][lane][j] = bf16(We[k][c*16+(lane&15)]) for k=(lane>>4)*8+j<16 else 0
__global__ void k_prep(const float* __restrict__ x, const float* __restrict__ Wcl,
                       const float* __restrict__ Wl1, const float* __restrict__ Wcr,
                       const float* __restrict__ Wr1, const float* __restrict__ We,
                       unsigned short* __restrict__ xb, int* __restrict__ deg,
                       int* __restrict__ cnt, unsigned short* __restrict__ Bp,
                       unsigned short* __restrict__ Bpwe, int N, long n4){
  long id = (long)blockIdx.x * blockDim.x + threadIdx.x;
  long nc4 = n4 / 4;
  if (id < nc4){
    long i4 = id * 4;
    float4 v = *(const float4*)(x + i4);
    ushort4 o; o.x = f2b(v.x); o.y = f2b(v.y); o.z = f2b(v.z); o.w = f2b(v.w);
    *(ushort4*)(xb + i4) = o;
    return;
  }
  id -= nc4;
  if (id < 2 * (long)N){
    if (id < N) deg[id] = 0; else cnt[id - N] = 0;
    return;
  }
  id -= 2 * (long)N;
  if (id < 4 * 2048){
    int mat = (int)(id >> 11), rem = (int)(id & 2047);
    int c = rem >> 8, q = (rem >> 6) & 3, l = rem & 63;
    const float* W = mat == 0 ? Wcl : mat == 1 ? Wl1 : mat == 2 ? Wcr : Wr1;
    unsigned short* o = Bp + ((size_t)mat * 2048 + rem) * 8;
    int kb = q * 32 + (l >> 4) * 8;
    int col = c * 16 + (l & 15);
    #pragma unroll
    for (int j = 0; j < 8; j++) o[j] = f2b(W[(kb + j) * 128 + col]);
    return;
  }
  id -= 4 * 2048;
  if (id < 2 * 8 * 64){
    int layer = (int)(id >> 9), rem = (int)(id & 511), c = rem >> 6, l = rem & 63;
    const float* W = We + (size_t)layer * 2048;
    unsigned short* o = Bpwe + (size_t)id * 8;
    int kb = (l >> 4) * 8;
    int col = c * 16 + (l & 15);
    #pragma unroll
    for (int j = 0; j < 8; j++){
      int k = kb + j;
      o[j] = (k < 16) ? f2b(W[k * 128 + col]) : (unsigned short)0;
    }
  }
}

// ---------------- fused pair GEMM: YL/YR[M,128](bf16) = A@WL+bL / A@WR+bR -------
__launch_bounds__(256)
__global__ void k_mm_lr(const unsigned short* __restrict__ A,
                        const unsigned short* __restrict__ BpL,
                        const unsigned short* __restrict__ BpR,
                        const float* __restrict__ bL, const float* __restrict__ bR,
                        unsigned short* __restrict__ YL, unsigned short* __restrict__ YR,
                        int M){
  const int ln = threadIdx.x & 63;
  const int rowBase = (blockIdx.x * 4 + (threadIdx.x >> 6)) * 16;
  const int r16 = ln & 15, quad = ln >> 4;
  int row = rowBase + r16; if (row >= M) row = M - 1;
  const unsigned short* ap = A + (size_t)row * 128 + quad * 8;
  s16x8 af[4];
  #pragma unroll
  for (int q = 0; q < 4; q++) af[q] = *(const s16x8*)(ap + q * 32);
  f32x4 aL[8], aR[8];
  #pragma unroll
  for (int c = 0; c < 8; c++){
    aL[c] = (f32x4){0.f, 0.f, 0.f, 0.f};
    aR[c] = (f32x4){0.f, 0.f, 0.f, 0.f};
    #pragma unroll
    for (int q = 0; q < 4; q++){
      s16x8 bfl = *(const s16x8*)(BpL + ((size_t)(c * 4 + q) * 64 + ln) * 8);
      s16x8 bfr = *(const s16x8*)(BpR + ((size_t)(c * 4 + q) * 64 + ln) * 8);
      aL[c] = __builtin_amdgcn_mfma_f32_16x16x32_bf16(af[q], bfl, aL[c], 0, 0, 0);
      aR[c] = __builtin_amdgcn_mfma_f32_16x16x32_bf16(af[q], bfr, aR[c], 0, 0, 0);
    }
  }
  #pragma unroll
  for (int c = 0; c < 8; c++){
    int col = c * 16 + r16;
    float bvl = bL[col], bvr = bR[col];
    #pragma unroll
    for (int r = 0; r < 4; r++){
      int orow = rowBase + quad * 4 + r;
      if (orow < M){
        YL[(size_t)orow * 128 + col] = f2b(aL[c][r] + bvl);
        YR[(size_t)orow * 128 + col] = f2b(aR[c][r] + bvr);
      }
    }
  }
}

// ---------------- Fused GAT layer ----------------
// Wave/node; lane t owns channels (2t,2t+1); head = t>>4.
// v7 = v6 + (a) xl/xr in bf16: gather rows 512B->256B (half the random
//      fetch lines; the dominant k_gat cost per FETCH_SIZE), unpack is the
//      same exact shift trick as ee; (b) next-node ptr prefetch (hides one
//      memory round trip per node).  ee tile: bf16 in LDS (16.25 KB/block).
// Self loop via linearity: ee_self = (sum_e ee_e)/max(deg,1).
__launch_bounds__(256)
__global__ void k_gat(const unsigned short* __restrict__ xl,
                      const unsigned short* __restrict__ xr,
                      const unsigned short* __restrict__ ceab,
                      const int* __restrict__ sx, const int* __restrict__ ptr,
                      const unsigned short* __restrict__ Bpwe,
                      const float* __restrict__ att, const float* __restrict__ cbv,
                      float* __restrict__ hf, unsigned short* __restrict__ hb,
                      int N, int wf, int wb){
  __shared__ unsigned short lee[4][16 * 130];   // bf16 ee, 16.25 KB total
  const int t = threadIdx.x & 63;
  const int wv = threadIdx.x >> 6;
  const int c0 = 2 * t;
  const int l15 = t & 15, q = t >> 4;
  const int stride = gridDim.x * 4;

  // We B-fragments (K=32, upper half zero) — loaded once, L2-cached
  s16x8 bwe[8];
  #pragma unroll
  for (int c = 0; c < 8; c++) bwe[c] = *(const s16x8*)(Bpwe + ((size_t)c * 64 + t) * 8);
  const f2 atv = *(const f2*)(att + c0);
  const f2 cbf = *(const f2*)(cbv + c0);
  unsigned short* lw = &lee[wv][0];
  const int wbase = q * 4 * 130 + l15;   // + r*130 + c*16 at write time

  int n = blockIdx.x * 4 + wv;
  int pb = 0, pe = 0;
  if (n < N){ pb = ptr[n]; pe = ptr[n + 1]; }
  while (n < N){
    // prefetch next node's CSR range (used next iteration)
    int nn = n + stride;
    int pb2 = 0, pe2 = 0;
    if (nn < N){ pb2 = ptr[nn]; pe2 = ptr[nn + 1]; }

    const int beg = __builtin_amdgcn_readfirstlane(pb);
    const int end = __builtin_amdgcn_readfirstlane(pe);
    const int deg = end - beg;

    const f2 xrv = b2f2(*(const au32*)(xr + (size_t)n * 128 + c0));
    const f2 xln = b2f2(*(const au32*)(xl + (size_t)n * 128 + c0));

    f2 acc = sp2(0.f), eesum = sp2(0.f);
    float den = 0.f;

    for (int cbase = beg; cbase < end; cbase += 64){
      const int cn = __builtin_amdgcn_readfirstlane(min(64, end - cbase));
      int sv = (t < cn) ? sx[cbase + t] : 0;

      for (int sub = 0; sub < cn; sub += 16){
        // A-fragment for this 16-edge tile: quad q element j <-> k=q*8+j.
        // Only quads 0,1 carry data (K=16); reads past cn hit ceab slack (masked).
        s16x8 af = (s16x8){0, 0, 0, 0, 0, 0, 0, 0};
        if (q < 2)
          af = *(const s16x8*)(ceab + (size_t)(cbase + sub + l15) * 16 + q * 8);
        // phase A: 16 independent bf16-pair gathers in flight (4B each)
        au32 xs[16];
        #pragma unroll
        for (int i = 0; i < 16; i++){
          int s = __builtin_amdgcn_readlane(sv, sub + i);  // 0 for invalid slots
          xs[i] = *(const au32*)(xl + (size_t)s * 128 + c0);
        }
        // ee tile on the matrix pipe; scatter C-frags to LDS as bf16
        #pragma unroll
        for (int c = 0; c < 8; c++){
          f32x4 ee4 = __builtin_amdgcn_mfma_f32_16x16x32_bf16(
              af, bwe[c], (f32x4){0.f, 0.f, 0.f, 0.f}, 0, 0, 0);
          #pragma unroll
          for (int r = 0; r < 4; r++)
            lw[wbase + r * 130 + c * 16] = f2b(ee4[r]);
        }
        // phase B: consume (1x ds_read_b32 = the lane's bf16 col-pair)
        #pragma unroll
        for (int i = 0; i < 16; i++){
          const int item = sub + i;
          const float vm = (item < cn) ? 1.f : 0.f;
          const int it = (item < cn) ? i : 0;      // clamp: row 0 is valid data
          au32 pp = *(const au32*)&lw[it * 130 + c0];
          f2 ee = b2f2(pp);
          f2 xv = b2f2(xs[i]);
          eesum = fma2(sp2(vm), ee, eesum);
          f2 m = xv + xrv + ee;
          m = fma2(sp2(NEG_SLOPE), min2(m, sp2(0.f)), max2(m, sp2(0.f)));
          f2 pr = m * atv;
          float pl = pr.x + pr.y;
          pl += __shfl_xor(pl, 1); pl += __shfl_xor(pl, 2);
          pl += __shfl_xor(pl, 4); pl += __shfl_xor(pl, 8);
          float p = __expf(pl) * vm;
          den += p;
          acc = fma2(sp2(p), xv, acc);
        }
      }
    }

    // self loop: ee_self = eesum / max(deg,1)
    {
      float rdeg = 1.f / fmaxf((float)deg, 1.f);
      f2 m = xln + xrv + eesum * sp2(rdeg);
      m = fma2(sp2(NEG_SLOPE), min2(m, sp2(0.f)), max2(m, sp2(0.f)));
      f2 pr = m * atv;
      float pl = pr.x + pr.y;
      pl += __shfl_xor(pl, 1); pl += __shfl_xor(pl, 2);
      pl += __shfl_xor(pl, 4); pl += __shfl_xor(pl, 8);
      float p = __expf(pl);
      den += p;
      acc = fma2(sp2(p), xln, acc);
    }

    float rd = 1.f / den;
    f2 o = fma2(acc, sp2(rd), cbf);
    float o0 = o.x > 0.f ? o.x : expm1f(o.x);
    float o1 = o.y > 0.f ? o.y : expm1f(o.y);
    if (wf) *(f2*)(hf + (size_t)n * 128 + c0) = (f2){o0, o1};
    if (wb){
      unsigned packed = (unsigned)f2b(o0) | ((unsigned)f2b(o1) << 16);
      *(unsigned*)(hb + (size_t)n * 128 + c0) = packed;
    }

    n = nn; pb = pb2; pe = pe2;
  }
}

// ---------------- LayerNorm + ReLU-MLP head ----------------
__launch_bounds__(256)
__global__ void k_head(const float* __restrict__ h, const float* __restrict__ g,
                       const float* __restrict__ b, const float* __restrict__ w1,
                       const float* __restrict__ b1, const float* __restrict__ w2,
                       const float* __restrict__ b2, float* __restrict__ out, int N){
  __shared__ float sn[4][128];
  const int t = threadIdx.x & 63, wv = threadIdx.x >> 6;
  for (int node = blockIdx.x * 4 + wv; node < N; node += gridDim.x * 4){
    float h0 = h[(size_t)node * 128 + t];
    float h1 = h[(size_t)node * 128 + 64 + t];
    float mu = wsum64(h0 + h1) * (1.f / 128.f);
    float d0 = h0 - mu, d1 = h1 - mu;
    float var = wsum64(d0 * d0 + d1 * d1) * (1.f / 128.f);
    float rstd = rsqrtf(var + LN_EPS);
    sn[wv][t]      = d0 * rstd * g[t]      + b[t];
    sn[wv][t + 64] = d1 * rstd * g[t + 64] + b[t + 64];
    float a = b1[t];
    #pragma unroll
    for (int k4 = 0; k4 < 32; k4++){
      float4 v = *(const float4*)&sn[wv][k4 * 4];
      a = fmaf(v.x, w1[(k4 * 4 + 0) * 64 + t], a);
      a = fmaf(v.y, w1[(k4 * 4 + 1) * 64 + t], a);
      a = fmaf(v.z, w1[(k4 * 4 + 2) * 64 + t], a);
      a = fmaf(v.w, w1[(k4 * 4 + 3) * 64 + t], a);
    }
    a = fmaxf(a, 0.f);
    float p0 = a * w2[t * 3 + 0], p1 = a * w2[t * 3 + 1], p2 = a * w2[t * 3 + 2];
    p0 = wsum64(p0); p1 = wsum64(p1); p2 = wsum64(p2);
    if (t == 0){
      out[(size_t)node * 3 + 0] = p0 + b2[0];
      out[(size_t)node * 3 + 1] = p1 + b2[1];
      out[(size_t)node * 3 + 2] = p2 + b2[2];
    }
  }
}

extern "C" void kernel_launch(void* const* d_in, const int* in_sizes, int n_in,
                              void* d_out, int out_size, void* d_ws, size_t ws_size,
                              hipStream_t stream){
  const float* x    = (const float*)d_in[0];
  const int*   ei   = (const int*)d_in[1];
  const float* ea   = (const float*)d_in[2];
  const float* in_w = (const float*)d_in[3];
  const float* in_b = (const float*)d_in[4];
  const float* Wl   = (const float*)d_in[5];
  const float* bl   = (const float*)d_in[6];
  const float* Wr   = (const float*)d_in[7];
  const float* br   = (const float*)d_in[8];
  const float* We   = (const float*)d_in[9];
  const float* att  = (const float*)d_in[10];
  const float* cb   = (const float*)d_in[11];
  const float* lng  = (const float*)d_in[12];
  const float* lnb  = (const float*)d_in[13];
  const float* h1w  = (const float*)d_in[14];
  const float* h1b  = (const float*)d_in[15];
  const float* h2w  = (const float*)d_in[16];
  const float* h2b  = (const float*)d_in[17];
  float* out = (float*)d_out;

  int N = in_sizes[0] / 128;
  int E = in_sizes[1] / 2;
  const int* src = ei;
  const int* dst = ei + E;

  char* w = (char*)d_ws;
  size_t off = 0;
  auto alloc = [&](size_t bytes) -> char* {
    char* p = w + off;
    off = (off + bytes + 255) & ~(size_t)255;
    return p;
  };
  int*   deg   = (int*)alloc((size_t)N * 4);
  int*   cnt   = (int*)alloc((size_t)N * 4);
  int*   ptr   = (int*)alloc((size_t)(N + 1) * 4);
  int*   bsum  = (int*)alloc(256 * 4);
  int*   sx    = (int*)alloc((size_t)E * 4);
  unsigned short* ceab = (unsigned short*)alloc((size_t)(E + 64) * 16 * 2); // bf16 CSR edge_attr (+slack)
  unsigned short* xb   = (unsigned short*)alloc((size_t)N * 128 * 2);  // x bf16
  unsigned short* g0   = (unsigned short*)alloc((size_t)N * 128 * 2);  // layer-0 gat out (bf16)
  unsigned short* Bp   = (unsigned short*)alloc((size_t)4 * 16384 * 2);
  unsigned short* Bpwe = (unsigned short*)alloc((size_t)2 * 4096 * 2);  // We K=32-padded frags
  float* Wcl  = (float*)alloc((size_t)16384 * 4);   // folded in_w@Wl0
  float* Wcr  = (float*)alloc((size_t)16384 * 4);   // folded in_w@Wr0
  float* bcl  = (float*)alloc(128 * 4);
  float* bcr  = (float*)alloc(128 * 4);
  float* hf   = (float*)alloc((size_t)N * 128 * 4);  // layer-1 gat out (fp32)
  unsigned short* xlb = (unsigned short*)alloc((size_t)N * 128 * 2);  // bf16
  unsigned short* xrb = (unsigned short*)alloc((size_t)N * 128 * 2);  // bf16

  // fold in-proj into layer-0 weights (tiny)
  k_fold<<<(2 * 16384 + 256 + 255) / 256, 256, 0, stream>>>(
      in_w, in_b, Wl, bl, Wr, br, Wcl, bcl, Wcr, bcr);

  // fused prep: cvt x->bf16, zero deg/cnt, pack Bp (4 mats), pack Bpwe
  long n4 = (long)N * 128;
  long total = n4 / 4 + 2 * (long)N + 4 * 2048 + 2 * 8 * 64;
  k_prep<<<(int)((total + 255) / 256), 256, 0, stream>>>(
      x, Wcl, Wl + 16384, Wcr, Wr + 16384, We, xb, deg, cnt, Bp, Bpwe, N, n4);

  int nb = (N + 255) / 256;
  k_count<<<(E + 255) / 256, 256, 0, stream>>>(dst, deg, E);
  k_scan_blk<<<nb, 256, 0, stream>>>(deg, ptr, bsum, N);
  k_scan_top<<<1, 256, 0, stream>>>(bsum, nb);
  k_scan_add<<<nb, 256, 0, stream>>>(ptr, bsum, N, E);
  k_fill<<<(E + 255) / 256, 256, 0, stream>>>(dst, src, cnt, ptr, ea, ceab, sx, E);

  int gblocks = (N + 63) / 64;
  int nodeBlocks = (N + 3) / 4;
  int gatBlocks = nodeBlocks < 2048 ? nodeBlocks : 2048;
  for (int l = 0; l < 2; l++){
    const unsigned short* Ain = (l == 0) ? xb : g0;
    const float* bLp = (l == 0) ? bcl : bl + 128;
    const float* bRp = (l == 0) ? bcr : br + 128;
    k_mm_lr<<<gblocks, 256, 0, stream>>>(Ain, Bp + (size_t)l * 16384,
                                         Bp + (size_t)(2 + l) * 16384,
                                         bLp, bRp, xlb, xrb, N);
    k_gat<<<gatBlocks, 256, 0, stream>>>(xlb, xrb, ceab, sx, ptr,
                                         Bpwe + (size_t)l * 4096,
                                         att + l * 128, cb + l * 128,
                                         hf, g0, N, (l == 1) ? 1 : 0, (l == 0) ? 1 : 0);
  }
  k_head<<<gatBlocks, 256, 0, stream>>>(hf, lng, lnb, h1w, h1b, h2w, h2b, out, N);
}

// Round 9
// 457.222 us; speedup vs baseline: 1.2981x; 1.0307x over previous
//
#include <hip/hip_runtime.h>

#define NEG_SLOPE 0.2f
#define LN_EPS 1e-5f

typedef float f2 __attribute__((ext_vector_type(2)));
typedef short s16x8 __attribute__((ext_vector_type(8)));
typedef float f32x4 __attribute__((ext_vector_type(4)));
typedef unsigned au32 __attribute__((may_alias));   // TBAA-safe bf16-pair read

__device__ __forceinline__ f2 sp2(float x){ return (f2){x, x}; }
__device__ __forceinline__ f2 fma2(f2 a, f2 b, f2 c){
#if __has_builtin(__builtin_elementwise_fma)
  return __builtin_elementwise_fma(a, b, c);
#else
  f2 r; r.x = fmaf(a.x, b.x, c.x); r.y = fmaf(a.y, b.y, c.y); return r;
#endif
}
__device__ __forceinline__ f2 max2(f2 a, f2 b){
#if __has_builtin(__builtin_elementwise_max)
  return __builtin_elementwise_max(a, b);
#else
  f2 r; r.x = fmaxf(a.x, b.x); r.y = fmaxf(a.y, b.y); return r;
#endif
}
__device__ __forceinline__ f2 min2(f2 a, f2 b){
#if __has_builtin(__builtin_elementwise_min)
  return __builtin_elementwise_min(a, b);
#else
  f2 r; r.x = fminf(a.x, b.x); r.y = fminf(a.y, b.y); return r;
#endif
}
__device__ __forceinline__ float wsum64(float v){
  #pragma unroll
  for (int o = 32; o >= 1; o >>= 1) v += __shfl_xor(v, o);
  return v;
}
// fp32 -> bf16 round-nearest-even (scalar; hot paths use v_cvt_pk_bf16_f32)
__device__ __forceinline__ unsigned short f2b(float f){
  unsigned u = __float_as_uint(f);
  return (unsigned short)((u + 0x7fffu + ((u >> 16) & 1u)) >> 16);
}
// 2x fp32 -> packed bf16 pair (lo=a, hi=b), RNE, single instruction
__device__ __forceinline__ unsigned cvtpk(float a, float b){
  unsigned r;
  asm("v_cvt_pk_bf16_f32 %0, %1, %2" : "=v"(r) : "v"(a), "v"(b));
  return r;
}
// unpack bf16 pair (u32) -> f2, exact
__device__ __forceinline__ f2 b2f2(unsigned pp){
  f2 r;
  r.x = __uint_as_float(pp << 16);
  r.y = __uint_as_float(pp & 0xffff0000u);
  return r;
}

// ---------------- CSR build ----------------
__global__ void k_count(const int* __restrict__ dst, int* __restrict__ deg, int E){
  int e = blockIdx.x * blockDim.x + threadIdx.x;
  if (e < E) atomicAdd(&deg[dst[e]], 1);
}

__global__ void k_scan_blk(const int* __restrict__ deg, int* __restrict__ part,
                           int* __restrict__ sums, int n){
  __shared__ int buf[256];
  int t = threadIdx.x, i = blockIdx.x * 256 + t;
  int v = (i < n) ? deg[i] : 0;
  buf[t] = v; __syncthreads();
  #pragma unroll
  for (int off = 1; off < 256; off <<= 1){
    int x = (t >= off) ? buf[t - off] : 0;
    __syncthreads(); buf[t] += x; __syncthreads();
  }
  if (i < n) part[i] = buf[t] - v;
  if (t == 255) sums[blockIdx.x] = buf[255];
}

__global__ void k_scan_top(int* __restrict__ sums, int nb){
  __shared__ int buf[256];
  int t = threadIdx.x;
  int v = (t < nb) ? sums[t] : 0;
  buf[t] = v; __syncthreads();
  #pragma unroll
  for (int off = 1; off < 256; off <<= 1){
    int x = (t >= off) ? buf[t - off] : 0;
    __syncthreads(); buf[t] += x; __syncthreads();
  }
  if (t < nb) sums[t] = buf[t] - v;
}

__global__ void k_scan_add(int* __restrict__ ptr, const int* __restrict__ sums,
                           int n, int Etot){
  int i = blockIdx.x * 256 + threadIdx.x;
  if (i < n) ptr[i] += sums[blockIdx.x];
  if (i == 0) ptr[n] = Etot;
}

// CSR fill: scatter src + edge_attr row (bf16, via cvt_pk) into CSR order.
__global__ void k_fill(const int* __restrict__ dst, const int* __restrict__ src,
                       int* __restrict__ cnt, const int* __restrict__ ptr,
                       const float* __restrict__ ea, unsigned short* __restrict__ ceab,
                       int* __restrict__ sx, int E){
  int e = blockIdx.x * blockDim.x + threadIdx.x;
  if (e < E){
    int d = dst[e];
    int pos = atomicAdd(&cnt[d], 1);
    int p = ptr[d] + pos;
    sx[p] = src[e];
    const float4* s4 = (const float4*)(ea + (size_t)e * 16);
    float4 a0 = s4[0], a1 = s4[1], a2 = s4[2], a3 = s4[3];
    uint4 o0 = {cvtpk(a0.x, a0.y), cvtpk(a0.z, a0.w),
                cvtpk(a1.x, a1.y), cvtpk(a1.z, a1.w)};
    uint4 o1 = {cvtpk(a2.x, a2.y), cvtpk(a2.z, a2.w),
                cvtpk(a3.x, a3.y), cvtpk(a3.z, a3.w)};
    uint4* d4 = (uint4*)(ceab + (size_t)p * 16);
    d4[0] = o0; d4[1] = o1;
  }
}

// ---------------- weight fold: Wc = in_w @ W0, bc = in_b @ W0 + b0 ----------------
__global__ void k_fold(const float* __restrict__ in_w, const float* __restrict__ in_b,
                       const float* __restrict__ Wl0, const float* __restrict__ bl0,
                       const float* __restrict__ Wr0, const float* __restrict__ br0,
                       float* __restrict__ Wcl, float* __restrict__ bcl,
                       float* __restrict__ Wcr, float* __restrict__ bcr){
  int id = blockIdx.x * blockDim.x + threadIdx.x;
  if (id < 2 * 16384){
    int m = id >> 14, rem = id & 16383;
    int k = rem >> 7, c = rem & 127;
    const float* W = m ? Wr0 : Wl0;
    float s = 0.f;
    #pragma unroll 4
    for (int d = 0; d < 128; d++) s = fmaf(in_w[k * 128 + d], W[d * 128 + c], s);
    (m ? Wcr : Wcl)[k * 128 + c] = s;
  } else if (id < 2 * 16384 + 256){
    int id2 = id - 2 * 16384;
    int m = id2 >> 7, c = id2 & 127;
    const float* W = m ? Wr0 : Wl0;
    float s = (m ? br0 : bl0)[c];
    for (int d = 0; d < 128; d++) s = fmaf(in_b[d], W[d * 128 + c], s);
    (m ? bcr : bcl)[c] = s;
  }
}

// ---------------- fused prep: cvt x->bf16, zero deg/cnt, pack 4 W mats, pack We ----
__global__ void k_prep(const float* __restrict__ x, const float* __restrict__ Wcl,
                       const float* __restrict__ Wl1, const float* __restrict__ Wcr,
                       const float* __restrict__ Wr1, const float* __restrict__ We,
                       unsigned short* __restrict__ xb, int* __restrict__ deg,
                       int* __restrict__ cnt, unsigned short* __restrict__ Bp,
                       unsigned short* __restrict__ Bpwe, int N, long n4){
  long id = (long)blockIdx.x * blockDim.x + threadIdx.x;
  long nc4 = n4 / 4;
  if (id < nc4){
    long i4 = id * 4;
    float4 v = *(const float4*)(x + i4);
    uint2 o = {cvtpk(v.x, v.y), cvtpk(v.z, v.w)};
    *(uint2*)(xb + i4) = o;
    return;
  }
  id -= nc4;
  if (id < 2 * (long)N){
    if (id < N) deg[id] = 0; else cnt[id - N] = 0;
    return;
  }
  id -= 2 * (long)N;
  if (id < 4 * 2048){
    int mat = (int)(id >> 11), rem = (int)(id & 2047);
    int c = rem >> 8, q = (rem >> 6) & 3, l = rem & 63;
    const float* W = mat == 0 ? Wcl : mat == 1 ? Wl1 : mat == 2 ? Wcr : Wr1;
    unsigned short* o = Bp + ((size_t)mat * 2048 + rem) * 8;
    int kb = q * 32 + (l >> 4) * 8;
    int col = c * 16 + (l & 15);
    #pragma unroll
    for (int j = 0; j < 8; j++) o[j] = f2b(W[(kb + j) * 128 + col]);
    return;
  }
  id -= 4 * 2048;
  if (id < 2 * 8 * 64){
    int layer = (int)(id >> 9), rem = (int)(id & 511), c = rem >> 6, l = rem & 63;
    const float* W = We + (size_t)layer * 2048;
    unsigned short* o = Bpwe + (size_t)id * 8;
    int kb = (l >> 4) * 8;
    int col = c * 16 + (l & 15);
    #pragma unroll
    for (int j = 0; j < 8; j++){
      int k = kb + j;
      o[j] = (k < 16) ? f2b(W[k * 128 + col]) : (unsigned short)0;
    }
  }
}

// ---------------- fused pair GEMM: YL/YR[M,128](bf16) = A@WL+bL / A@WR+bR -------
__launch_bounds__(256)
__global__ void k_mm_lr(const unsigned short* __restrict__ A,
                        const unsigned short* __restrict__ BpL,
                        const unsigned short* __restrict__ BpR,
                        const float* __restrict__ bL, const float* __restrict__ bR,
                        unsigned short* __restrict__ YL, unsigned short* __restrict__ YR,
                        int M){
  const int ln = threadIdx.x & 63;
  const int rowBase = (blockIdx.x * 4 + (threadIdx.x >> 6)) * 16;
  const int r16 = ln & 15, quad = ln >> 4;
  int row = rowBase + r16; if (row >= M) row = M - 1;
  const unsigned short* ap = A + (size_t)row * 128 + quad * 8;
  s16x8 af[4];
  #pragma unroll
  for (int q = 0; q < 4; q++) af[q] = *(const s16x8*)(ap + q * 32);
  f32x4 aL[8], aR[8];
  #pragma unroll
  for (int c = 0; c < 8; c++){
    aL[c] = (f32x4){0.f, 0.f, 0.f, 0.f};
    aR[c] = (f32x4){0.f, 0.f, 0.f, 0.f};
    #pragma unroll
    for (int q = 0; q < 4; q++){
      s16x8 bfl = *(const s16x8*)(BpL + ((size_t)(c * 4 + q) * 64 + ln) * 8);
      s16x8 bfr = *(const s16x8*)(BpR + ((size_t)(c * 4 + q) * 64 + ln) * 8);
      aL[c] = __builtin_amdgcn_mfma_f32_16x16x32_bf16(af[q], bfl, aL[c], 0, 0, 0);
      aR[c] = __builtin_amdgcn_mfma_f32_16x16x32_bf16(af[q], bfr, aR[c], 0, 0, 0);
    }
  }
  const int orow = rowBase + quad * 4;
  #pragma unroll
  for (int c = 0; c < 8; c++){
    int col = c * 16 + r16;
    float bvl = bL[col], bvr = bR[col];
    unsigned l01 = cvtpk(aL[c][0] + bvl, aL[c][1] + bvl);
    unsigned l23 = cvtpk(aL[c][2] + bvl, aL[c][3] + bvl);
    unsigned r01 = cvtpk(aR[c][0] + bvr, aR[c][1] + bvr);
    unsigned r23 = cvtpk(aR[c][2] + bvr, aR[c][3] + bvr);
    if (orow     < M) YL[(size_t)(orow    ) * 128 + col] = (unsigned short)l01;
    if (orow + 1 < M) YL[(size_t)(orow + 1) * 128 + col] = (unsigned short)(l01 >> 16);
    if (orow + 2 < M) YL[(size_t)(orow + 2) * 128 + col] = (unsigned short)l23;
    if (orow + 3 < M) YL[(size_t)(orow + 3) * 128 + col] = (unsigned short)(l23 >> 16);
    if (orow     < M) YR[(size_t)(orow    ) * 128 + col] = (unsigned short)r01;
    if (orow + 1 < M) YR[(size_t)(orow + 1) * 128 + col] = (unsigned short)(r01 >> 16);
    if (orow + 2 < M) YR[(size_t)(orow + 2) * 128 + col] = (unsigned short)r23;
    if (orow + 3 < M) YR[(size_t)(orow + 3) * 128 + col] = (unsigned short)(r23 >> 16);
  }
}

// ---------------- Fused GAT layer ----------------
// Wave/node; lane t owns channels (2t,2t+1); head = t>>4.
// v8: VALU-cut round (k_gat was VALU-issue-bound at 63%):
//  - ee scatter via v_cvt_pk_bf16_f32 (1 inst per 2 values vs ~10 for f2b pair)
//  - A-fragment rows >= cn masked to ZERO -> invalid tile rows are exact 0,
//    so phase B reads LDS at compile-time immediate offsets (no clamp/select)
//    and eesum adds unconditionally.
//  - output always packed bf16 (cvt_pk, single u32 store); hf is bf16 now.
// Self loop via linearity: ee_self = (sum_e ee_e)/max(deg,1).
__launch_bounds__(256)
__global__ void k_gat(const unsigned short* __restrict__ xl,
                      const unsigned short* __restrict__ xr,
                      const unsigned short* __restrict__ ceab,
                      const int* __restrict__ sx, const int* __restrict__ ptr,
                      const unsigned short* __restrict__ Bpwe,
                      const float* __restrict__ att, const float* __restrict__ cbv,
                      unsigned* __restrict__ outp, int N){
  __shared__ unsigned short lee[4][16 * 130];   // bf16 ee, 16.25 KB total
  const int t = threadIdx.x & 63;
  const int wv = threadIdx.x >> 6;
  const int c0 = 2 * t;
  const int l15 = t & 15, q = t >> 4;
  const int stride = gridDim.x * 4;

  // We B-fragments (K=32, upper half zero) — loaded once, L2-cached
  s16x8 bwe[8];
  #pragma unroll
  for (int c = 0; c < 8; c++) bwe[c] = *(const s16x8*)(Bpwe + ((size_t)c * 64 + t) * 8);
  const f2 atv = *(const f2*)(att + c0);
  const f2 cbf = *(const f2*)(cbv + c0);
  unsigned short* lw = &lee[wv][0];
  const int wbase = q * 4 * 130 + l15;   // + r*130 + c*16 at write time

  int n = blockIdx.x * 4 + wv;
  int pb = 0, pe = 0;
  if (n < N){ pb = ptr[n]; pe = ptr[n + 1]; }
  while (n < N){
    int nn = n + stride;
    int pb2 = 0, pe2 = 0;
    if (nn < N){ pb2 = ptr[nn]; pe2 = ptr[nn + 1]; }

    const int beg = __builtin_amdgcn_readfirstlane(pb);
    const int end = __builtin_amdgcn_readfirstlane(pe);
    const int deg = end - beg;

    const f2 xrv = b2f2(*(const au32*)(xr + (size_t)n * 128 + c0));
    const f2 xln = b2f2(*(const au32*)(xl + (size_t)n * 128 + c0));

    f2 acc = sp2(0.f), eesum = sp2(0.f);
    float den = 0.f;

    for (int cbase = beg; cbase < end; cbase += 64){
      const int cn = __builtin_amdgcn_readfirstlane(min(64, end - cbase));
      int sv = (t < cn) ? sx[cbase + t] : 0;

      for (int sub = 0; sub < cn; sub += 16){
        // A-fragment: quad q element j <-> k=q*8+j; rows >= cn zeroed so the
        // MFMA output for invalid rows is exactly 0 (enables unguarded reads).
        s16x8 af = (s16x8){0, 0, 0, 0, 0, 0, 0, 0};
        if (q < 2 && sub + l15 < cn)
          af = *(const s16x8*)(ceab + (size_t)(cbase + sub + l15) * 16 + q * 8);
        // phase A: 16 independent bf16-pair gathers in flight (4B each)
        au32 xs[16];
        #pragma unroll
        for (int i = 0; i < 16; i++){
          int s = __builtin_amdgcn_readlane(sv, sub + i);  // 0 for invalid slots
          xs[i] = *(const au32*)(xl + (size_t)s * 128 + c0);
        }
        // ee tile on the matrix pipe; scatter C-frags to LDS via cvt_pk
        #pragma unroll
        for (int c = 0; c < 8; c++){
          f32x4 ee4 = __builtin_amdgcn_mfma_f32_16x16x32_bf16(
              af, bwe[c], (f32x4){0.f, 0.f, 0.f, 0.f}, 0, 0, 0);
          unsigned p01 = cvtpk(ee4[0], ee4[1]);
          unsigned p23 = cvtpk(ee4[2], ee4[3]);
          lw[wbase + 0 * 130 + c * 16] = (unsigned short)p01;
          lw[wbase + 1 * 130 + c * 16] = (unsigned short)(p01 >> 16);
          lw[wbase + 2 * 130 + c * 16] = (unsigned short)p23;
          lw[wbase + 3 * 130 + c * 16] = (unsigned short)(p23 >> 16);
        }
        // phase B: consume (imm-offset ds_read_b32; invalid rows are exact 0)
        #pragma unroll
        for (int i = 0; i < 16; i++){
          const float vm = (sub + i < cn) ? 1.f : 0.f;
          au32 pp = *(const au32*)&lw[i * 130 + c0];
          f2 ee = b2f2(pp);
          f2 xv = b2f2(xs[i]);
          eesum += ee;                       // invalid rows contribute exact 0
          f2 m = xv + xrv + ee;
          m = fma2(sp2(NEG_SLOPE), min2(m, sp2(0.f)), max2(m, sp2(0.f)));
          f2 pr = m * atv;
          float pl = pr.x + pr.y;
          pl += __shfl_xor(pl, 1); pl += __shfl_xor(pl, 2);
          pl += __shfl_xor(pl, 4); pl += __shfl_xor(pl, 8);
          float p = __expf(pl) * vm;
          den += p;
          acc = fma2(sp2(p), xv, acc);
        }
      }
    }

    // self loop: ee_self = eesum / max(deg,1)
    {
      float rdeg = 1.f / fmaxf((float)deg, 1.f);
      f2 m = xln + xrv + eesum * sp2(rdeg);
      m = fma2(sp2(NEG_SLOPE), min2(m, sp2(0.f)), max2(m, sp2(0.f)));
      f2 pr = m * atv;
      float pl = pr.x + pr.y;
      pl += __shfl_xor(pl, 1); pl += __shfl_xor(pl, 2);
      pl += __shfl_xor(pl, 4); pl += __shfl_xor(pl, 8);
      float p = __expf(pl);
      den += p;
      acc = fma2(sp2(p), xln, acc);
    }

    float rd = 1.f / den;
    f2 o = fma2(acc, sp2(rd), cbf);
    float o0 = o.x > 0.f ? o.x : expm1f(o.x);
    float o1 = o.y > 0.f ? o.y : expm1f(o.y);
    outp[(size_t)n * 64 + t] = cvtpk(o0, o1);

    n = nn; pb = pb2; pe = pe2;
  }
}

// ---------------- LayerNorm + ReLU-MLP head (bf16 input) ----------------
__launch_bounds__(256)
__global__ void k_head(const unsigned short* __restrict__ h, const float* __restrict__ g,
                       const float* __restrict__ b, const float* __restrict__ w1,
                       const float* __restrict__ b1, const float* __restrict__ w2,
                       const float* __restrict__ b2, float* __restrict__ out, int N){
  __shared__ float sn[4][128];
  const int t = threadIdx.x & 63, wv = threadIdx.x >> 6;
  for (int node = blockIdx.x * 4 + wv; node < N; node += gridDim.x * 4){
    unsigned short u0 = h[(size_t)node * 128 + t];
    unsigned short u1 = h[(size_t)node * 128 + 64 + t];
    float h0 = __uint_as_float(((unsigned)u0) << 16);
    float h1 = __uint_as_float(((unsigned)u1) << 16);
    float mu = wsum64(h0 + h1) * (1.f / 128.f);
    float d0 = h0 - mu, d1 = h1 - mu;
    float var = wsum64(d0 * d0 + d1 * d1) * (1.f / 128.f);
    float rstd = rsqrtf(var + LN_EPS);
    sn[wv][t]      = d0 * rstd * g[t]      + b[t];
    sn[wv][t + 64] = d1 * rstd * g[t + 64] + b[t + 64];
    float a = b1[t];
    #pragma unroll
    for (int k4 = 0; k4 < 32; k4++){
      float4 v = *(const float4*)&sn[wv][k4 * 4];
      a = fmaf(v.x, w1[(k4 * 4 + 0) * 64 + t], a);
      a = fmaf(v.y, w1[(k4 * 4 + 1) * 64 + t], a);
      a = fmaf(v.z, w1[(k4 * 4 + 2) * 64 + t], a);
      a = fmaf(v.w, w1[(k4 * 4 + 3) * 64 + t], a);
    }
    a = fmaxf(a, 0.f);
    float p0 = a * w2[t * 3 + 0], p1 = a * w2[t * 3 + 1], p2 = a * w2[t * 3 + 2];
    p0 = wsum64(p0); p1 = wsum64(p1); p2 = wsum64(p2);
    if (t == 0){
      out[(size_t)node * 3 + 0] = p0 + b2[0];
      out[(size_t)node * 3 + 1] = p1 + b2[1];
      out[(size_t)node * 3 + 2] = p2 + b2[2];
    }
  }
}

extern "C" void kernel_launch(void* const* d_in, const int* in_sizes, int n_in,
                              void* d_out, int out_size, void* d_ws, size_t ws_size,
                              hipStream_t stream){
  const float* x    = (const float*)d_in[0];
  const int*   ei   = (const int*)d_in[1];
  const float* ea   = (const float*)d_in[2];
  const float* in_w = (const float*)d_in[3];
  const float* in_b = (const float*)d_in[4];
  const float* Wl   = (const float*)d_in[5];
  const float* bl   = (const float*)d_in[6];
  const float* Wr   = (const float*)d_in[7];
  const float* br   = (const float*)d_in[8];
  const float* We   = (const float*)d_in[9];
  const float* att  = (const float*)d_in[10];
  const float* cb   = (const float*)d_in[11];
  const float* lng  = (const float*)d_in[12];
  const float* lnb  = (const float*)d_in[13];
  const float* h1w  = (const float*)d_in[14];
  const float* h1b  = (const float*)d_in[15];
  const float* h2w  = (const float*)d_in[16];
  const float* h2b  = (const float*)d_in[17];
  float* out = (float*)d_out;

  int N = in_sizes[0] / 128;
  int E = in_sizes[1] / 2;
  const int* src = ei;
  const int* dst = ei + E;

  char* w = (char*)d_ws;
  size_t off = 0;
  auto alloc = [&](size_t bytes) -> char* {
    char* p = w + off;
    off = (off + bytes + 255) & ~(size_t)255;
    return p;
  };
  int*   deg   = (int*)alloc((size_t)N * 4);
  int*   cnt   = (int*)alloc((size_t)N * 4);
  int*   ptr   = (int*)alloc((size_t)(N + 1) * 4);
  int*   bsum  = (int*)alloc(256 * 4);
  int*   sx    = (int*)alloc((size_t)E * 4);
  unsigned short* ceab = (unsigned short*)alloc((size_t)(E + 64) * 16 * 2); // bf16 CSR edge_attr (+slack)
  unsigned short* xb   = (unsigned short*)alloc((size_t)N * 128 * 2);  // x bf16
  unsigned short* g0   = (unsigned short*)alloc((size_t)N * 128 * 2);  // layer-0 gat out (bf16)
  unsigned short* hf16 = (unsigned short*)alloc((size_t)N * 128 * 2);  // layer-1 gat out (bf16)
  unsigned short* Bp   = (unsigned short*)alloc((size_t)4 * 16384 * 2);
  unsigned short* Bpwe = (unsigned short*)alloc((size_t)2 * 4096 * 2);  // We K=32-padded frags
  float* Wcl  = (float*)alloc((size_t)16384 * 4);   // folded in_w@Wl0
  float* Wcr  = (float*)alloc((size_t)16384 * 4);   // folded in_w@Wr0
  float* bcl  = (float*)alloc(128 * 4);
  float* bcr  = (float*)alloc(128 * 4);
  unsigned short* xlb = (unsigned short*)alloc((size_t)N * 128 * 2);  // bf16
  unsigned short* xrb = (unsigned short*)alloc((size_t)N * 128 * 2);  // bf16

  // fold in-proj into layer-0 weights (tiny)
  k_fold<<<(2 * 16384 + 256 + 255) / 256, 256, 0, stream>>>(
      in_w, in_b, Wl, bl, Wr, br, Wcl, bcl, Wcr, bcr);

  // fused prep: cvt x->bf16, zero deg/cnt, pack Bp (4 mats), pack Bpwe
  long n4 = (long)N * 128;
  long total = n4 / 4 + 2 * (long)N + 4 * 2048 + 2 * 8 * 64;
  k_prep<<<(int)((total + 255) / 256), 256, 0, stream>>>(
      x, Wcl, Wl + 16384, Wcr, Wr + 16384, We, xb, deg, cnt, Bp, Bpwe, N, n4);

  int nb = (N + 255) / 256;
  k_count<<<(E + 255) / 256, 256, 0, stream>>>(dst, deg, E);
  k_scan_blk<<<nb, 256, 0, stream>>>(deg, ptr, bsum, N);
  k_scan_top<<<1, 256, 0, stream>>>(bsum, nb);
  k_scan_add<<<nb, 256, 0, stream>>>(ptr, bsum, N, E);
  k_fill<<<(E + 255) / 256, 256, 0, stream>>>(dst, src, cnt, ptr, ea, ceab, sx, E);

  int gblocks = (N + 63) / 64;
  int nodeBlocks = (N + 3) / 4;
  int gatBlocks = nodeBlocks < 2048 ? nodeBlocks : 2048;
  for (int l = 0; l < 2; l++){
    const unsigned short* Ain = (l == 0) ? xb : g0;
    const float* bLp = (l == 0) ? bcl : bl + 128;
    const float* bRp = (l == 0) ? bcr : br + 128;
    unsigned* outp = (unsigned*)((l == 0) ? g0 : hf16);
    k_mm_lr<<<gblocks, 256, 0, stream>>>(Ain, Bp + (size_t)l * 16384,
                                         Bp + (size_t)(2 + l) * 16384,
                                         bLp, bRp, xlb, xrb, N);
    k_gat<<<gatBlocks, 256, 0, stream>>>(xlb, xrb, ceab, sx, ptr,
                                         Bpwe + (size_t)l * 4096,
                                         att + l * 128, cb + l * 128,
                                         outp, N);
  }
  k_head<<<gatBlocks, 256, 0, stream>>>(hf16, lng, lnb, h1w, h1b, h2w, h2b, out, N);
}